// Round 5
// baseline (1766.375 us; speedup 1.0000x reference)
//
#include <hip/hip_runtime.h>
#include <stdint.h>

// ---------------- problem constants ----------------
#define PB 16            // batches
#define PN 8192          // points per batch
#define PG 512           // FPS samples (centers) per batch
#define PK 32            // knn group size
#define PTOK 384
#define PM (PB*PG)       // 8192 groups total
#define PMK (PM*PK)      // 262144 MLP rows
static constexpr float BN_EPS_C = 1e-5f;

typedef short bh8  __attribute__((ext_vector_type(8)));
typedef float f32x4 __attribute__((ext_vector_type(4)));

__device__ __forceinline__ short f2bf(float f){
  unsigned u = __float_as_uint(f);
  unsigned r = u + 0x7fffu + ((u>>16)&1u);   // RNE
  return (short)(r>>16);
}
__device__ __forceinline__ float bf2f(short s){
  return __uint_as_float(((unsigned)(unsigned short)s)<<16);
}
__device__ __forceinline__ void gload16(const void* g, void* l){
  __builtin_amdgcn_global_load_lds((const __attribute__((address_space(1))) unsigned int*)g,
                                   (__attribute__((address_space(3))) unsigned int*)l,
                                   16, 0, 0);
}

// ---------------- 1. FPS: 1024 thr/batch, 8 pts/thread in VGPRs ----------------
// key = (bits(md)<<32) | (PN-1-j): u64 max == (max md, tie -> lowest j) == numpy argmax.
// Cross-wave reduce: one ds_read_b64 (lane reads slot lane&15) + 4-step shfl_xor
// butterfly => winner in every lane; replaces 16-slot scan per wave (R4's LDS
// throughput bottleneck: ~300 LDS ops/CU/round -> ~80).
__global__ __launch_bounds__(1024, 4) void fps_kernel(const float* __restrict__ points,
                                                      float* __restrict__ centers){
#pragma clang fp contract(off)
  const int b = blockIdx.x;
  const int t = threadIdx.x;
  const float* P = points + (size_t)b*PN*3;
  __shared__ float Lx[PN], Ly[PN], Lz[PN];         // 96 KB coord mirror
  __shared__ unsigned long long swk[2][16];
  float px[8], py[8], pz[8], md[8];
#pragma unroll
  for (int i=0;i<8;i++){
    int j = i*1024 + t;
    float x=P[j*3+0], y=P[j*3+1], z=P[j*3+2];
    px[i]=x; py[i]=y; pz[i]=z; md[i]=1e10f;
    Lx[j]=x; Ly[j]=y; Lz[j]=z;
  }
  float cx=P[0], cy=P[1], cz=P[2];                 // start index 0
  if (t==0){ float* c = centers + (size_t)b*PG*3; c[0]=cx; c[1]=cy; c[2]=cz; }
  const int lane = t & 63, wid = t >> 6;
  __syncthreads();
  for (int g=1; g<PG; g++){
    float bv=-1.0f; int bi=0;
#pragma unroll
    for (int i=0;i<8;i++){
      float dx=px[i]-cx, dy=py[i]-cy, dz=pz[i]-cz;
      float d2 = (dx*dx + dy*dy) + dz*dz;          // numpy order, no fma
      md[i] = fminf(md[i], d2);
      if (md[i] > bv){ bv = md[i]; bi = i*1024 + t; }   // ascending i => lowest idx on tie
    }
    unsigned long long bk = ((unsigned long long)__float_as_uint(bv)<<32)
                          | (unsigned)(PN-1 - bi);
#pragma unroll
    for (int off=32; off; off>>=1){
      unsigned long long o = __shfl_down(bk, off);
      if (o > bk) bk = o;
    }
    if (lane==0) swk[g&1][wid] = bk;
    __syncthreads();                               // the only barrier per round
    unsigned long long w = swk[g&1][lane & 15];    // one b64 read covers all 16 slots
#pragma unroll
    for (int mask=8; mask; mask>>=1){
      unsigned long long o = __shfl_xor(w, mask);  // butterfly within 16-lane group
      if (o > w) w = o;
    }
    int j = PN-1 - (int)(w & 0xFFFFFFFFu);
    cx = Lx[j]; cy = Ly[j]; cz = Lz[j];            // broadcast reads (same addr)
    if (t==0){ float* c = centers + ((size_t)b*PG + g)*3; c[0]=cx; c[1]=cy; c[2]=cz; }
  }
}

// ---------------- 2. KNN: exact top-32 set, keys fully in VGPRs ----------------
__global__ __launch_bounds__(256) void knn_kernel(const float* __restrict__ points,
                                                  const float* __restrict__ centers,
                                                  float* __restrict__ groups){
#pragma clang fp contract(off)
  const int m = blockIdx.x;
  const int b = m >> 9;       // m / PG
  const int t = threadIdx.x;
  const float* P = points + (size_t)b*PN*3;
  const float* c = centers + (size_t)m*3;
  const float cx=c[0], cy=c[1], cz=c[2];
  const float cn = (cx*cx + cy*cy) + cz*cz;
  unsigned long long key[PK];
#pragma unroll
  for (int i=0;i<PK;i++){
    int j = i*256 + t;
    float x=P[j*3+0], y=P[j*3+1], z=P[j*3+2];
    float pn = (x*x + y*y) + z*z;
    float e  = (cx*x + cy*y) + cz*z;
    float d2 = (cn + pn) - 2.0f*e;                 // reference formula
    unsigned u = __float_as_uint(d2);
    u ^= (u & 0x80000000u) ? 0xFFFFFFFFu : 0x80000000u;   // total order
    key[i] = ((unsigned long long)u << 32) | (unsigned)j;
  }
  __shared__ unsigned long long swk[2][4];
  __shared__ int s_idx[PK];
  const int lane = t & 63, wid = t >> 6;
  for (int it=0; it<PK; it++){
    unsigned long long v = key[0];
#pragma unroll
    for (int i=1;i<PK;i++) if (key[i] < v) v = key[i];   // static, stays in VGPRs
#pragma unroll
    for (int off=32; off; off>>=1){
      unsigned long long o = __shfl_down(v, off);
      if (o < v) v = o;
    }
    if (lane==0) swk[it&1][wid] = v;
    __syncthreads();                               // the only barrier per round
    unsigned long long w = swk[it&1][0];
#pragma unroll
    for (int q=1;q<4;q++) if (swk[it&1][q] < w) w = swk[it&1][q];
    if (t==0) s_idx[it] = (int)(w & 0xFFFFFFFFull);
#pragma unroll
    for (int i=0;i<PK;i++) if (key[i] == w) key[i] = ~0ull;  // branch-free removal
  }
  __syncthreads();
  if (t < PK*3){
    int k = t/3, cc = t - k*3;
    int j = s_idx[k];
    groups[((size_t)m*PK + k)*3 + cc] = P[j*3+cc] - c[cc];
  }
}

// ---------------- 3. layer1: 3->128 linear + BN1 + ReLU, fp32 VALU ----------------
__global__ __launch_bounds__(256) void layer1_kernel(const float* __restrict__ groups,
                                                     const float* __restrict__ w1,
                                                     const float* __restrict__ sc1,
                                                     const float* __restrict__ sh1,
                                                     short* __restrict__ f1){
  int idx = blockIdx.x*256 + threadIdx.x;   // [mk, d], d fastest (slice-local)
  int d  = idx & 127;
  int mk = idx >> 7;
  const float* x = groups + (size_t)mk*3;
  float a = x[0]*w1[d*3+0] + x[1]*w1[d*3+1] + x[2]*w1[d*3+2];
  float y = a*sc1[d] + sh1[d];
  f1[idx] = f2bf(fmaxf(y, 0.f));
}

// ---------------- 4. bf16 MFMA GEMM: C[M,N] = A[M,K] @ B[N,K]^T, m97 structure ----
// EPI 0: store fp32 raw (H). EPI 1: +bias[col], store bf16. EPI 2: relu(bn2(acc+H[row/32])) bf16.
template<int EPI>
__global__ __launch_bounds__(256) void gemm_bt(const short* __restrict__ A,
                                               const short* __restrict__ Bw,
                                               float* __restrict__ Cf,
                                               short* __restrict__ Cb,
                                               int Nn, int Kd,
                                               const float* __restrict__ aux0,
                                               const float* __restrict__ scale,
                                               const float* __restrict__ shift){
  __shared__ __align__(16) short As[128*32];
  __shared__ __align__(16) short Bs[128*32];
  const int bm = blockIdx.x, bn = blockIdx.y;
  const int t = threadIdx.x;
  const int lane = t & 63, wid = t >> 6;
  const int wr = wid >> 1, wc = wid & 1;          // 2x2 waves, each 64x64
  f32x4 acc[4][4] = {};
  const int srow = lane >> 2;                      // staging: row within 16-row chunk
  const int scol = (lane & 3) * 8;                 // staging: 8-elem column offset
  const int frow = lane & 15;                      // fragment row/col
  const int fk   = (lane >> 4) * 8;                // fragment k offset
  for (int k0 = 0; k0 < Kd; k0 += 32){
    const size_t abase = ((size_t)bm*128) * Kd + k0 + scol;
    const size_t bbase = ((size_t)bn*128) * Kd + k0 + scol;
    for (int q=0;q<2;q++){
      int chunk = wid*2 + q;                       // 8 chunks x 16 rows = 128 rows
      gload16(A  + abase + (size_t)(chunk*16 + srow)*Kd, &As[chunk*512]);
      gload16(Bw + bbase + (size_t)(chunk*16 + srow)*Kd, &Bs[chunk*512]);
    }
    __syncthreads();                               // vmcnt(0) drained by compiler
    bh8 af[4], bf[4];
    for (int i=0;i<4;i++) af[i] = *(const bh8*)&As[(wr*64 + i*16 + frow)*32 + fk];
    for (int j=0;j<4;j++) bf[j] = *(const bh8*)&Bs[(wc*64 + j*16 + frow)*32 + fk];
    for (int i=0;i<4;i++)
      for (int j=0;j<4;j++)
        acc[i][j] = __builtin_amdgcn_mfma_f32_16x16x32_bf16(af[i], bf[j], acc[i][j], 0, 0, 0);
    __syncthreads();                               // protect LDS for next stage
  }
  const int rb = (lane >> 4) * 4;                  // C/D: col=lane&15, row=(lane>>4)*4+reg
  const int cb = lane & 15;
  for (int i=0;i<4;i++){
    for (int j=0;j<4;j++){
      int col = bn*128 + wc*64 + j*16 + cb;
      for (int r=0;r<4;r++){
        size_t row = (size_t)bm*128 + wr*64 + i*16 + rb + r;
        float v = acc[i][j][r];
        if (EPI == 0){
          Cf[row*Nn + col] = v;
        } else if (EPI == 1){
          Cb[row*Nn + col] = f2bf(v + aux0[col]);
        } else {
          v += aux0[(row >> 5)*Nn + col];          // + g@w3a^T per group (slice-local)
          v = v*scale[col] + shift[col];           // BN2
          Cb[row*Nn + col] = f2bf(fmaxf(v, 0.f));  // ReLU
        }
      }
    }
  }
}

// ---------------- 5. max-pools ----------------
__global__ __launch_bounds__(256) void maxpool_g_kernel(const short* __restrict__ f2,
                                                        short* __restrict__ g){
  int m = blockIdx.x, c = threadIdx.x;
  float mx = -3.4e38f;
  for (int k=0;k<PK;k++) mx = fmaxf(mx, bf2f(f2[((size_t)m*PK + k)*256 + c]));
  g[(size_t)m*256 + c] = f2bf(mx);  // lossless: max of bf16 values
}
__global__ __launch_bounds__(384) void maxpool_t_kernel(const short* __restrict__ f4,
                                                        float* __restrict__ tok){
  int m = blockIdx.x, c = threadIdx.x;
  float mx = -3.4e38f;
  for (int k=0;k<PK;k++) mx = fmaxf(mx, bf2f(f4[((size_t)m*PK + k)*PTOK + c]));
  tok[(size_t)m*PTOK + c] = mx;
}

// ---------------- 0. weight conversion + BN folding ----------------
__global__ __launch_bounds__(256) void prep_kernel(const float* __restrict__ w2,
    const float* __restrict__ w3, const float* __restrict__ w4,
    const float* __restrict__ g1, const float* __restrict__ be1,
    const float* __restrict__ mu1, const float* __restrict__ va1,
    const float* __restrict__ g2, const float* __restrict__ be2,
    const float* __restrict__ mu2, const float* __restrict__ va2,
    short* __restrict__ w2b, short* __restrict__ w3ab, short* __restrict__ w3bb,
    short* __restrict__ w4b, float* __restrict__ sc1, float* __restrict__ sh1,
    float* __restrict__ sc2, float* __restrict__ sh2){
  int i = blockIdx.x*256 + threadIdx.x;
  if (i < 256*128) w2b[i] = f2bf(w2[i]);
  if (i < 512*512){
    int f = i >> 9, e = i & 511;
    short v = f2bf(w3[i]);
    if (e < 256) w3ab[f*256 + e] = v; else w3bb[f*256 + (e-256)] = v;
  }
  if (i < 384*512) w4b[i] = f2bf(w4[i]);
  if (i < 128){ float s = g1[i]*rsqrtf(va1[i] + BN_EPS_C); sc1[i]=s; sh1[i]=be1[i]-mu1[i]*s; }
  if (i < 512){ float s = g2[i]*rsqrtf(va2[i] + BN_EPS_C); sc2[i]=s; sh2[i]=be2[i]-mu2[i]*s; }
}

// ---------------- launcher ----------------
extern "C" void kernel_launch(void* const* d_in, const int* in_sizes, int n_in,
                              void* d_out, int out_size, void* d_ws, size_t ws_size,
                              hipStream_t stream){
  const float* points = (const float*)d_in[0];
  const float* w1  = (const float*)d_in[1];
  const float* g1  = (const float*)d_in[2];
  const float* be1 = (const float*)d_in[3];
  const float* mu1 = (const float*)d_in[4];
  const float* va1 = (const float*)d_in[5];
  const float* w2  = (const float*)d_in[6];
  const float* b2  = (const float*)d_in[7];
  const float* w3  = (const float*)d_in[8];
  const float* g2  = (const float*)d_in[9];
  const float* be2 = (const float*)d_in[10];
  const float* mu2 = (const float*)d_in[11];
  const float* va2 = (const float*)d_in[12];
  const float* w4  = (const float*)d_in[13];
  const float* b4  = (const float*)d_in[14];
  float* tokens  = (float*)d_out;                       // [PM, 384]
  float* centers = (float*)d_out + (size_t)PM*PTOK;     // [PM, 3]

  // ---- fixed workspace region (~25.1 MB) ----
  char* ws = (char*)d_ws;
  float* grp  = (float*)(ws + 0);              // 262144x3 fp32  = 3 MB
  short* gbuf = (short*)(ws + 3145728ull);     // 8192x256 bf16  = 4 MB
  float* Hbuf = (float*)(ws + 7340032ull);     // 8192x512 fp32  = 16 MB
  short* w2b  = (short*)(ws + 24117248ull);    // 256x128 bf16
  short* w3ab = (short*)(ws + 24182784ull);    // 512x256 bf16
  short* w3bb = (short*)(ws + 24444928ull);    // 512x256 bf16
  short* w4b  = (short*)(ws + 24707072ull);    // 384x512 bf16
  float* sc1  = (float*)(ws + 25100288ull);
  float* sh1  = (float*)(ws + 25100800ull);
  float* sc2  = (float*)(ws + 25101312ull);
  float* sh2  = (float*)(ws + 25103360ull);
  const size_t sliceBase = 25105408ull;

  // ---- adaptive row-slicing: peak slice use = 1792 bytes/row ----
  size_t avail = (ws_size > sliceBase) ? (ws_size - sliceBase) : 0;
  long long smax = (long long)(avail / 1792u);
  int S = (int)((smax / 4096) * 4096);
  if (S > PMK) S = PMK;
  if (S < 4096) S = 4096;   // below ~32 MB ws nothing fits; best effort
  char* sl = ws + sliceBase;

  prep_kernel<<<1024, 256, 0, stream>>>(w2, w3, w4, g1, be1, mu1, va1, g2, be2, mu2, va2,
                                        w2b, w3ab, w3bb, w4b, sc1, sh1, sc2, sh2);
  fps_kernel<<<PB, 1024, 0, stream>>>(points, centers);
  knn_kernel<<<PM, 256, 0, stream>>>(points, centers, grp);

  for (int r0 = 0; r0 < PMK; r0 += S){
    int rows = (PMK - r0 < S) ? (PMK - r0) : S;    // multiple of 4096
    int g0 = r0 >> 5, ng = rows >> 5;              // groups in slice
    short* f1 = (short*)(sl + 0);                  // rows x 128 bf16
    short* f2 = (short*)(sl + (size_t)S*256);      // rows x 256 bf16
    short* f3 = (short*)(sl + (size_t)S*768);      // rows x 512 bf16
    short* f4 = (short*)(sl + 0);                  // rows x 384 bf16 (aliases f1+f2, both dead)

    layer1_kernel<<<(rows*128)/256, 256, 0, stream>>>(grp + (size_t)r0*3, w1, sc1, sh1, f1);
    // f2 = f1 @ w2^T + b2
    gemm_bt<1><<<dim3(rows/128, 2), 256, 0, stream>>>(f1, w2b, nullptr, f2, 256, 128,
                                                      b2, nullptr, nullptr);
    // g = maxpool_k(f2)
    maxpool_g_kernel<<<ng, 256, 0, stream>>>(f2, gbuf + (size_t)g0*256);
    // H = g @ w3[:, :256]^T   (per-group part of the concat GEMM)
    gemm_bt<0><<<dim3(ng/128, 4), 256, 0, stream>>>(gbuf + (size_t)g0*256, w3ab,
                                                    Hbuf + (size_t)g0*512, nullptr, 512, 256,
                                                    nullptr, nullptr, nullptr);
    // f3 = relu(bn2(f2 @ w3[:, 256:]^T + H[group]))
    gemm_bt<2><<<dim3(rows/128, 4), 256, 0, stream>>>(f2, w3bb, nullptr, f3, 512, 256,
                                                      Hbuf + (size_t)g0*512, sc2, sh2);
    // f4 = f3 @ w4^T + b4
    gemm_bt<1><<<dim3(rows/128, 3), 256, 0, stream>>>(f3, w4b, nullptr, f4, 384, 512,
                                                      b4, nullptr, nullptr);
    // tokens = maxpool_k(f4)
    maxpool_t_kernel<<<ng, 384, 0, stream>>>(f4, tokens + (size_t)g0*384);
  }
}

// Round 7
// 1665.449 us; speedup vs baseline: 1.0606x; 1.0606x over previous
//
#include <hip/hip_runtime.h>
#include <stdint.h>

// ---------------- problem constants ----------------
#define PB 16            // batches
#define PN 8192          // points per batch
#define PG 512           // FPS samples (centers) per batch
#define PK 32            // knn group size
#define PTOK 384
#define PM (PB*PG)       // 8192 groups total
#define PMK (PM*PK)      // 262144 MLP rows
static constexpr float BN_EPS_C = 1e-5f;

typedef short bh8  __attribute__((ext_vector_type(8)));
typedef float f32x4 __attribute__((ext_vector_type(4)));

__device__ __forceinline__ short f2bf(float f){
  unsigned u = __float_as_uint(f);
  unsigned r = u + 0x7fffu + ((u>>16)&1u);   // RNE
  return (short)(r>>16);
}
__device__ __forceinline__ float bf2f(short s){
  return __uint_as_float(((unsigned)(unsigned short)s)<<16);
}
__device__ __forceinline__ void gload16(const void* g, void* l){
  __builtin_amdgcn_global_load_lds((const __attribute__((address_space(1))) unsigned int*)g,
                                   (__attribute__((address_space(3))) unsigned int*)l,
                                   16, 0, 0);
}

// ---------------- 1. FPS: 1024 thr/batch, 8 pts/thread in VGPRs ----------------
// EXACT R5 version (known-pass, bit-exact centers). u64 key = (bits(md)<<32)|(PN-1-j):
// u64 max == (max md, tie -> lowest j) == numpy argmax.
__global__ __launch_bounds__(1024, 4) void fps_kernel(const float* __restrict__ points,
                                                      float* __restrict__ centers){
#pragma clang fp contract(off)
  const int b = blockIdx.x;
  const int t = threadIdx.x;
  const float* P = points + (size_t)b*PN*3;
  __shared__ float Lx[PN], Ly[PN], Lz[PN];         // 96 KB coord mirror
  __shared__ unsigned long long swk[2][16];
  float px[8], py[8], pz[8], md[8];
#pragma unroll
  for (int i=0;i<8;i++){
    int j = i*1024 + t;
    float x=P[j*3+0], y=P[j*3+1], z=P[j*3+2];
    px[i]=x; py[i]=y; pz[i]=z; md[i]=1e10f;
    Lx[j]=x; Ly[j]=y; Lz[j]=z;
  }
  float cx=P[0], cy=P[1], cz=P[2];                 // start index 0
  if (t==0){ float* c = centers + (size_t)b*PG*3; c[0]=cx; c[1]=cy; c[2]=cz; }
  const int lane = t & 63, wid = t >> 6;
  __syncthreads();
  for (int g=1; g<PG; g++){
    float bv=-1.0f; int bi=0;
#pragma unroll
    for (int i=0;i<8;i++){
      float dx=px[i]-cx, dy=py[i]-cy, dz=pz[i]-cz;
      float d2 = (dx*dx + dy*dy) + dz*dz;          // numpy order, no fma
      md[i] = fminf(md[i], d2);
      if (md[i] > bv){ bv = md[i]; bi = i*1024 + t; }   // ascending i => lowest idx on tie
    }
    unsigned long long bk = ((unsigned long long)__float_as_uint(bv)<<32)
                          | (unsigned)(PN-1 - bi);
#pragma unroll
    for (int off=32; off; off>>=1){
      unsigned long long o = __shfl_down(bk, off);
      if (o > bk) bk = o;
    }
    if (lane==0) swk[g&1][wid] = bk;
    __syncthreads();                               // the only barrier per round
    unsigned long long w = swk[g&1][lane & 15];    // one b64 read covers all 16 slots
#pragma unroll
    for (int mask=8; mask; mask>>=1){
      unsigned long long o = __shfl_xor(w, mask);  // butterfly within 16-lane group
      if (o > w) w = o;
    }
    int j = PN-1 - (int)(w & 0xFFFFFFFFu);
    cx = Lx[j]; cy = Ly[j]; cz = Lz[j];            // broadcast reads (same addr)
    if (t==0){ float* c = centers + ((size_t)b*PG + g)*3; c[0]=cx; c[1]=cy; c[2]=cz; }
  }
}

// ---------------- 2. KNN: exact top-32 set, keys fully in VGPRs ----------------
__global__ __launch_bounds__(256) void knn_kernel(const float* __restrict__ points,
                                                  const float* __restrict__ centers,
                                                  float* __restrict__ groups){
#pragma clang fp contract(off)
  const int m = blockIdx.x;
  const int b = m >> 9;       // m / PG
  const int t = threadIdx.x;
  const float* P = points + (size_t)b*PN*3;
  const float* c = centers + (size_t)m*3;
  const float cx=c[0], cy=c[1], cz=c[2];
  const float cn = (cx*cx + cy*cy) + cz*cz;
  unsigned long long key[PK];
#pragma unroll
  for (int i=0;i<PK;i++){
    int j = i*256 + t;
    float x=P[j*3+0], y=P[j*3+1], z=P[j*3+2];
    float pn = (x*x + y*y) + z*z;
    float e  = (cx*x + cy*y) + cz*z;
    float d2 = (cn + pn) - 2.0f*e;                 // reference formula
    unsigned u = __float_as_uint(d2);
    u ^= (u & 0x80000000u) ? 0xFFFFFFFFu : 0x80000000u;   // total order
    key[i] = ((unsigned long long)u << 32) | (unsigned)j;
  }
  __shared__ unsigned long long swk[2][4];
  __shared__ int s_idx[PK];
  const int lane = t & 63, wid = t >> 6;
  for (int it=0; it<PK; it++){
    unsigned long long v = key[0];
#pragma unroll
    for (int i=1;i<PK;i++) if (key[i] < v) v = key[i];   // static, stays in VGPRs
#pragma unroll
    for (int off=32; off; off>>=1){
      unsigned long long o = __shfl_down(v, off);
      if (o < v) v = o;
    }
    if (lane==0) swk[it&1][wid] = v;
    __syncthreads();                               // the only barrier per round
    unsigned long long w = swk[it&1][0];
#pragma unroll
    for (int q=1;q<4;q++) if (swk[it&1][q] < w) w = swk[it&1][q];
    if (t==0) s_idx[it] = (int)(w & 0xFFFFFFFFull);
#pragma unroll
    for (int i=0;i<PK;i++) if (key[i] == w) key[i] = ~0ull;  // branch-free removal
  }
  __syncthreads();
  if (t < PK*3){
    int k = t/3, cc = t - k*3;
    int j = s_idx[k];
    groups[((size_t)m*PK + k)*3 + cc] = P[j*3+cc] - c[cc];
  }
}

// ---------------- 3. layer1: 3->128 linear + BN1 + ReLU, fp32 VALU ----------------
__global__ __launch_bounds__(256) void layer1_kernel(const float* __restrict__ groups,
                                                     const float* __restrict__ w1,
                                                     const float* __restrict__ sc1,
                                                     const float* __restrict__ sh1,
                                                     short* __restrict__ f1){
  int idx = blockIdx.x*256 + threadIdx.x;   // [mk, d], d fastest (slice-local)
  int d  = idx & 127;
  int mk = idx >> 7;
  const float* x = groups + (size_t)mk*3;
  float a = x[0]*w1[d*3+0] + x[1]*w1[d*3+1] + x[2]*w1[d*3+2];
  float y = a*sc1[d] + sh1[d];
  f1[idx] = f2bf(fmaxf(y, 0.f));
}

// ---------------- 4. bf16 MFMA GEMM: C[M,N] = A[M,K] @ B[N,K]^T ----------------
// EPI 0: store fp32 raw (H).
// EPI 1: +bias[col], store bf16.
// EPI 2: relu(bn2(acc+H[row/32])), store bf16.
// EPI 3: +bias, store bf16 AND fused k-maxpool -> pool_bf (128 rows = 4 groups).
// EPI 4: +bias, fused k-maxpool only -> pool_f (f4 never materialized).
template<int EPI>
__global__ __launch_bounds__(256) void gemm_bt(const short* __restrict__ A,
                                               const short* __restrict__ Bw,
                                               float* __restrict__ Cf,
                                               short* __restrict__ Cb,
                                               int Nn, int Kd,
                                               const float* __restrict__ aux0,
                                               const float* __restrict__ scale,
                                               const float* __restrict__ shift,
                                               short* __restrict__ pool_bf,
                                               float* __restrict__ pool_f){
  __shared__ __align__(16) short smem[(EPI>=3) ? 16384 : 8192];   // 32 KB / 16 KB
  short* As = smem;
  short* Bs = smem + 4096;
  const int bm = blockIdx.x, bn = blockIdx.y;
  const int t = threadIdx.x;
  const int lane = t & 63, wid = t >> 6;
  const int wr = wid >> 1, wc = wid & 1;          // 2x2 waves, each 64x64
  f32x4 acc[4][4] = {};
  const int srow = lane >> 2;                      // staging: row within 16-row chunk
  const int scol = (lane & 3) * 8;                 // staging: 8-elem column offset
  const int frow = lane & 15;                      // fragment row/col
  const int fk   = (lane >> 4) * 8;                // fragment k offset
  for (int k0 = 0; k0 < Kd; k0 += 32){
    const size_t abase = ((size_t)bm*128) * Kd + k0 + scol;
    const size_t bbase = ((size_t)bn*128) * Kd + k0 + scol;
    for (int q=0;q<2;q++){
      int chunk = wid*2 + q;                       // 8 chunks x 16 rows = 128 rows
      gload16(A  + abase + (size_t)(chunk*16 + srow)*Kd, &As[chunk*512]);
      gload16(Bw + bbase + (size_t)(chunk*16 + srow)*Kd, &Bs[chunk*512]);
    }
    __syncthreads();                               // vmcnt(0) drained by compiler
    bh8 af[4], bf[4];
    for (int i=0;i<4;i++) af[i] = *(const bh8*)&As[(wr*64 + i*16 + frow)*32 + fk];
    for (int j=0;j<4;j++) bf[j] = *(const bh8*)&Bs[(wc*64 + j*16 + frow)*32 + fk];
    for (int i=0;i<4;i++)
      for (int j=0;j<4;j++)
        acc[i][j] = __builtin_amdgcn_mfma_f32_16x16x32_bf16(af[i], bf[j], acc[i][j], 0, 0, 0);
    __syncthreads();                               // protect LDS for next stage
  }
  const int rb = (lane >> 4) * 4;                  // C/D: col=lane&15, row=(lane>>4)*4+reg
  const int cb = lane & 15;
  for (int i=0;i<4;i++){
    for (int j=0;j<4;j++){
      int lcol = wc*64 + j*16 + cb;
      int col  = bn*128 + lcol;
      for (int r=0;r<4;r++){
        int lrow = wr*64 + i*16 + rb + r;
        size_t row = (size_t)bm*128 + lrow;
        float v = acc[i][j][r];
        if (EPI == 0){
          Cf[row*Nn + col] = v;
        } else if (EPI == 1){
          Cb[row*Nn + col] = f2bf(v + aux0[col]);
        } else if (EPI == 2){
          v += aux0[(row >> 5)*Nn + col];          // + g@w3a^T per group (slice-local)
          v = v*scale[col] + shift[col];           // BN2
          Cb[row*Nn + col] = f2bf(fmaxf(v, 0.f));  // ReLU
        } else {
          short bv = f2bf(v + aux0[col]);
          if (EPI == 3) Cb[row*Nn + col] = bv;     // f2 still needed downstream
          smem[lrow*128 + lcol] = bv;              // stage tile for fused pool
        }
      }
    }
  }
  if (EPI >= 3){
    __syncthreads();                               // tile complete in LDS
    int c = t & 127, gsel = t >> 7;                // 256 thr -> 2 (group,col) each
#pragma unroll
    for (int gg=0; gg<2; gg++){
      int g = gsel*2 + gg;                         // 0..3 within tile
      float mx = -3.4e38f;
#pragma unroll
      for (int k=0;k<PK;k++) mx = fmaxf(mx, bf2f(smem[(g*32 + k)*128 + c]));
      size_t grow = (size_t)bm*4 + g;
      int gcol = bn*128 + c;
      if (EPI == 3) pool_bf[grow*256  + gcol] = f2bf(mx);
      else          pool_f [grow*PTOK + gcol] = mx;
    }
  }
}

// ---------------- 0. weight conversion + BN folding ----------------
__global__ __launch_bounds__(256) void prep_kernel(const float* __restrict__ w2,
    const float* __restrict__ w3, const float* __restrict__ w4,
    const float* __restrict__ g1, const float* __restrict__ be1,
    const float* __restrict__ mu1, const float* __restrict__ va1,
    const float* __restrict__ g2, const float* __restrict__ be2,
    const float* __restrict__ mu2, const float* __restrict__ va2,
    short* __restrict__ w2b, short* __restrict__ w3ab, short* __restrict__ w3bb,
    short* __restrict__ w4b, float* __restrict__ sc1, float* __restrict__ sh1,
    float* __restrict__ sc2, float* __restrict__ sh2){
  int i = blockIdx.x*256 + threadIdx.x;
  if (i < 256*128) w2b[i] = f2bf(w2[i]);
  if (i < 512*512){
    int f = i >> 9, e = i & 511;
    short v = f2bf(w3[i]);
    if (e < 256) w3ab[f*256 + e] = v; else w3bb[f*256 + (e-256)] = v;
  }
  if (i < 384*512) w4b[i] = f2bf(w4[i]);
  if (i < 128){ float s = g1[i]*rsqrtf(va1[i] + BN_EPS_C); sc1[i]=s; sh1[i]=be1[i]-mu1[i]*s; }
  if (i < 512){ float s = g2[i]*rsqrtf(va2[i] + BN_EPS_C); sc2[i]=s; sh2[i]=be2[i]-mu2[i]*s; }
}

// ---------------- launcher ----------------
extern "C" void kernel_launch(void* const* d_in, const int* in_sizes, int n_in,
                              void* d_out, int out_size, void* d_ws, size_t ws_size,
                              hipStream_t stream){
  const float* points = (const float*)d_in[0];
  const float* w1  = (const float*)d_in[1];
  const float* g1  = (const float*)d_in[2];
  const float* be1 = (const float*)d_in[3];
  const float* mu1 = (const float*)d_in[4];
  const float* va1 = (const float*)d_in[5];
  const float* w2  = (const float*)d_in[6];
  const float* b2  = (const float*)d_in[7];
  const float* w3  = (const float*)d_in[8];
  const float* g2  = (const float*)d_in[9];
  const float* be2 = (const float*)d_in[10];
  const float* mu2 = (const float*)d_in[11];
  const float* va2 = (const float*)d_in[12];
  const float* w4  = (const float*)d_in[13];
  const float* b4  = (const float*)d_in[14];
  float* tokens  = (float*)d_out;                       // [PM, 384]
  float* centers = (float*)d_out + (size_t)PM*PTOK;     // [PM, 3]

  // ---- fixed workspace region (~25.1 MB) ----
  char* ws = (char*)d_ws;
  float* grp  = (float*)(ws + 0);              // 262144x3 fp32  = 3 MB
  short* gbuf = (short*)(ws + 3145728ull);     // 8192x256 bf16  = 4 MB
  float* Hbuf = (float*)(ws + 7340032ull);     // 8192x512 fp32  = 16 MB
  short* w2b  = (short*)(ws + 24117248ull);    // 256x128 bf16
  short* w3ab = (short*)(ws + 24182784ull);    // 512x256 bf16
  short* w3bb = (short*)(ws + 24444928ull);    // 512x256 bf16
  short* w4b  = (short*)(ws + 24707072ull);    // 384x512 bf16
  float* sc1  = (float*)(ws + 25100288ull);
  float* sh1  = (float*)(ws + 25100800ull);
  float* sc2  = (float*)(ws + 25101312ull);
  float* sh2  = (float*)(ws + 25103360ull);
  const size_t sliceBase = 25105408ull;

  // ---- adaptive row-slicing: peak slice use = 1792 bytes/row ----
  size_t avail = (ws_size > sliceBase) ? (ws_size - sliceBase) : 0;
  long long smax = (long long)(avail / 1792u);
  int S = (int)((smax / 4096) * 4096);
  if (S > PMK) S = PMK;
  if (S < 4096) S = 4096;   // below ~32 MB ws nothing fits; best effort
  char* sl = ws + sliceBase;

  prep_kernel<<<1024, 256, 0, stream>>>(w2, w3, w4, g1, be1, mu1, va1, g2, be2, mu2, va2,
                                        w2b, w3ab, w3bb, w4b, sc1, sh1, sc2, sh2);
  fps_kernel<<<PB, 1024, 0, stream>>>(points, centers);
  knn_kernel<<<PM, 256, 0, stream>>>(points, centers, grp);

  for (int r0 = 0; r0 < PMK; r0 += S){
    int rows = (PMK - r0 < S) ? (PMK - r0) : S;    // multiple of 4096
    int g0 = r0 >> 5, ng = rows >> 5;              // groups in slice
    short* f1 = (short*)(sl + 0);                  // rows x 128 bf16
    short* f2 = (short*)(sl + (size_t)S*256);      // rows x 256 bf16
    short* f3 = (short*)(sl + (size_t)S*768);      // rows x 512 bf16

    layer1_kernel<<<(rows*128)/256, 256, 0, stream>>>(grp + (size_t)r0*3, w1, sc1, sh1, f1);
    // f2 = f1 @ w2^T + b2, fused g = maxpool_k(f2)
    gemm_bt<3><<<dim3(rows/128, 2), 256, 0, stream>>>(f1, w2b, nullptr, f2, 256, 128,
                                                      b2, nullptr, nullptr,
                                                      gbuf + (size_t)g0*256, nullptr);
    // H = g @ w3[:, :256]^T   (per-group part of the concat GEMM)
    gemm_bt<0><<<dim3(ng/128, 4), 256, 0, stream>>>(gbuf + (size_t)g0*256, w3ab,
                                                    Hbuf + (size_t)g0*512, nullptr, 512, 256,
                                                    nullptr, nullptr, nullptr, nullptr, nullptr);
    // f3 = relu(bn2(f2 @ w3[:, 256:]^T + H[group]))
    gemm_bt<2><<<dim3(rows/128, 4), 256, 0, stream>>>(f2, w3bb, nullptr, f3, 512, 256,
                                                      Hbuf + (size_t)g0*512, sc2, sh2,
                                                      nullptr, nullptr);
    // tokens = maxpool_k(f3 @ w4^T + b4), f4 never materialized
    gemm_bt<4><<<dim3(rows/128, 3), 256, 0, stream>>>(f3, w4b, nullptr, nullptr, 384, 512,
                                                      b4, nullptr, nullptr,
                                                      nullptr, tokens + (size_t)g0*384);
  }
}

// Round 8
// 1482.535 us; speedup vs baseline: 1.1915x; 1.1234x over previous
//
#include <hip/hip_runtime.h>
#include <stdint.h>

// ---------------- problem constants ----------------
#define PB 16            // batches
#define PN 8192          // points per batch
#define PG 512           // FPS samples (centers) per batch
#define PK 32            // knn group size
#define PTOK 384
#define PM (PB*PG)       // 8192 groups total
#define PMK (PM*PK)      // 262144 MLP rows
static constexpr float BN_EPS_C = 1e-5f;

typedef short bh8  __attribute__((ext_vector_type(8)));
typedef float f32x4 __attribute__((ext_vector_type(4)));

__device__ __forceinline__ short f2bf(float f){
  unsigned u = __float_as_uint(f);
  unsigned r = u + 0x7fffu + ((u>>16)&1u);   // RNE
  return (short)(r>>16);
}
__device__ __forceinline__ float bf2f(short s){
  return __uint_as_float(((unsigned)(unsigned short)s)<<16);
}
__device__ __forceinline__ void gload16(const void* g, void* l){
  __builtin_amdgcn_global_load_lds((const __attribute__((address_space(1))) unsigned int*)g,
                                   (__attribute__((address_space(3))) unsigned int*)l,
                                   16, 0, 0);
}

// ---------------- 1. FPS: value-only f32 reduce + exact index resolve ----------
// Round: (a) md update + thread max (no index tracking), (b) f32 wave reduce +
// butterfly -> wmax in every lane, (c) threads with md[i]==wmax atomicMin their
// lowest j into an LDS slot (min-j == numpy first-index argmax, exact on ties;
// equality is bitwise safe: wmax is propagated unmodified through fmin/fmax).
// Two barriers/round, double-buffered slots; reset of the other buffer is
// ordered by the barriers (analyzed: reads of sj[sl^1] finished before B2_g).
__global__ __launch_bounds__(1024, 4) void fps_kernel(const float* __restrict__ points,
                                                      float* __restrict__ centers){
#pragma clang fp contract(off)
  const int b = blockIdx.x;
  const int t = threadIdx.x;
  const float* P = points + (size_t)b*PN*3;
  __shared__ float Lx[PN], Ly[PN], Lz[PN];         // 96 KB coord mirror
  __shared__ float swv[2][16];
  __shared__ unsigned sj[2];
  float px[8], py[8], pz[8], md[8];
#pragma unroll
  for (int i=0;i<8;i++){
    int j = i*1024 + t;
    float x=P[j*3+0], y=P[j*3+1], z=P[j*3+2];
    px[i]=x; py[i]=y; pz[i]=z; md[i]=1e10f;
    Lx[j]=x; Ly[j]=y; Lz[j]=z;
  }
  float cx=P[0], cy=P[1], cz=P[2];                 // start index 0
  if (t==0){
    float* c = centers + (size_t)b*PG*3; c[0]=cx; c[1]=cy; c[2]=cz;
    sj[0] = 0xFFFFFFFFu; sj[1] = 0xFFFFFFFFu;
  }
  const int lane = t & 63, wid = t >> 6;
  __syncthreads();
  for (int g=1; g<PG; g++){
    const int sl = g & 1;
    float bv = -1.0f;
#pragma unroll
    for (int i=0;i<8;i++){
      float dx=px[i]-cx, dy=py[i]-cy, dz=pz[i]-cz;
      float d2 = (dx*dx + dy*dy) + dz*dz;          // numpy order, no fma
      md[i] = fminf(md[i], d2);
      bv = fmaxf(bv, md[i]);                       // value only — no index
    }
#pragma unroll
    for (int off=32; off; off>>=1)
      bv = fmaxf(bv, __shfl_down(bv, off));
    if (lane==0) swv[sl][wid] = bv;
    __syncthreads();                               // B1: wave maxes published
    float wmax = swv[sl][lane & 15];
#pragma unroll
    for (int mask=8; mask; mask>>=1)
      wmax = fmaxf(wmax, __shfl_xor(wmax, mask));  // all lanes hold block max
    unsigned bi = 0xFFFFFFFFu;
#pragma unroll
    for (int i=7;i>=0;i--)                         // descending => lowest i survives
      if (md[i] == wmax) bi = (unsigned)(i*1024 + t);
    if (bi != 0xFFFFFFFFu) atomicMin(&sj[sl], bi); // rare: ~1 thread per round
    __syncthreads();                               // B2: winner index final
    unsigned j = sj[sl];
    if (t==0) sj[sl^1] = 0xFFFFFFFFu;              // reset buffer for next round
    cx = Lx[j]; cy = Ly[j]; cz = Lz[j];            // broadcast reads (same addr)
    if (t==0){ float* c = centers + ((size_t)b*PG + g)*3; c[0]=cx; c[1]=cy; c[2]=cz; }
  }
}

// ---------------- 2. KNN: exact top-32, incremental lmin + owner rescan --------
// Running per-thread min (lmin) replaces the 32-wide scan each round; only the
// owner of the extracted key (j&255==t) redoes the static knockout+rescan in a
// divergent branch (execz skips 3 of 4 waves). All indices static => VGPRs.
__global__ __launch_bounds__(256) void knn_kernel(const float* __restrict__ points,
                                                  const float* __restrict__ centers,
                                                  float* __restrict__ groups){
#pragma clang fp contract(off)
  const int m = blockIdx.x;
  const int b = m >> 9;       // m / PG
  const int t = threadIdx.x;
  const float* P = points + (size_t)b*PN*3;
  const float* c = centers + (size_t)m*3;
  const float cx=c[0], cy=c[1], cz=c[2];
  const float cn = (cx*cx + cy*cy) + cz*cz;
  unsigned long long key[PK];
#pragma unroll
  for (int i=0;i<PK;i++){
    int j = i*256 + t;
    float x=P[j*3+0], y=P[j*3+1], z=P[j*3+2];
    float pn = (x*x + y*y) + z*z;
    float e  = (cx*x + cy*y) + cz*z;
    float d2 = (cn + pn) - 2.0f*e;                 // reference formula
    unsigned u = __float_as_uint(d2);
    u ^= (u & 0x80000000u) ? 0xFFFFFFFFu : 0x80000000u;   // total order
    key[i] = ((unsigned long long)u << 32) | (unsigned)j;
  }
  unsigned long long lmin = key[0];
#pragma unroll
  for (int i=1;i<PK;i++) if (key[i] < lmin) lmin = key[i];
  __shared__ unsigned long long swk[2][4];
  __shared__ int s_idx[PK];
  const int lane = t & 63, wid = t >> 6;
  for (int it=0; it<PK; it++){
    unsigned long long v = lmin;
#pragma unroll
    for (int off=32; off; off>>=1){
      unsigned long long o = __shfl_down(v, off);
      if (o < v) v = o;
    }
    if (lane==0) swk[it&1][wid] = v;
    __syncthreads();                               // the only barrier per round
    unsigned long long w = swk[it&1][0];
#pragma unroll
    for (int q=1;q<4;q++) if (swk[it&1][q] < w) w = swk[it&1][q];
    int wj = (int)(w & 0xFFFFFFFFull);
    if (t==0) s_idx[it] = wj;
    if ((wj & 255) == t){                          // owner-only knockout + rescan
#pragma unroll
      for (int i=0;i<PK;i++) if (key[i] == w) key[i] = ~0ull;
      lmin = key[0];
#pragma unroll
      for (int i=1;i<PK;i++) if (key[i] < lmin) lmin = key[i];
    }
  }
  __syncthreads();
  if (t < PK*3){
    int k = t/3, cc = t - k*3;
    int j = s_idx[k];
    groups[((size_t)m*PK + k)*3 + cc] = P[j*3+cc] - c[cc];
  }
}

// ---------------- 3. layer1: 3->128 linear + BN1 + ReLU, fp32 VALU ----------------
__global__ __launch_bounds__(256) void layer1_kernel(const float* __restrict__ groups,
                                                     const float* __restrict__ w1,
                                                     const float* __restrict__ sc1,
                                                     const float* __restrict__ sh1,
                                                     short* __restrict__ f1){
  int idx = blockIdx.x*256 + threadIdx.x;   // [mk, d], d fastest (slice-local)
  int d  = idx & 127;
  int mk = idx >> 7;
  const float* x = groups + (size_t)mk*3;
  float a = x[0]*w1[d*3+0] + x[1]*w1[d*3+1] + x[2]*w1[d*3+2];
  float y = a*sc1[d] + sh1[d];
  f1[idx] = f2bf(fmaxf(y, 0.f));
}

// ---------------- 4. bf16 MFMA GEMM: C[M,N] = A[M,K] @ B[N,K]^T ----------------
// EPI 0: store fp32 raw (H).
// EPI 1: +bias[col], store bf16.
// EPI 2: relu(bn2(acc+H[row/32])), store bf16.
// EPI 3: +bias, store bf16 AND fused k-maxpool -> pool_bf (128 rows = 4 groups).
// EPI 4: +bias, fused k-maxpool only -> pool_f (f4 never materialized).
template<int EPI>
__global__ __launch_bounds__(256) void gemm_bt(const short* __restrict__ A,
                                               const short* __restrict__ Bw,
                                               float* __restrict__ Cf,
                                               short* __restrict__ Cb,
                                               int Nn, int Kd,
                                               const float* __restrict__ aux0,
                                               const float* __restrict__ scale,
                                               const float* __restrict__ shift,
                                               short* __restrict__ pool_bf,
                                               float* __restrict__ pool_f){
  __shared__ __align__(16) short smem[(EPI>=3) ? 16384 : 8192];   // 32 KB / 16 KB
  short* As = smem;
  short* Bs = smem + 4096;
  const int bm = blockIdx.x, bn = blockIdx.y;
  const int t = threadIdx.x;
  const int lane = t & 63, wid = t >> 6;
  const int wr = wid >> 1, wc = wid & 1;          // 2x2 waves, each 64x64
  f32x4 acc[4][4] = {};
  const int srow = lane >> 2;                      // staging: row within 16-row chunk
  const int scol = (lane & 3) * 8;                 // staging: 8-elem column offset
  const int frow = lane & 15;                      // fragment row/col
  const int fk   = (lane >> 4) * 8;                // fragment k offset
  for (int k0 = 0; k0 < Kd; k0 += 32){
    const size_t abase = ((size_t)bm*128) * Kd + k0 + scol;
    const size_t bbase = ((size_t)bn*128) * Kd + k0 + scol;
    for (int q=0;q<2;q++){
      int chunk = wid*2 + q;                       // 8 chunks x 16 rows = 128 rows
      gload16(A  + abase + (size_t)(chunk*16 + srow)*Kd, &As[chunk*512]);
      gload16(Bw + bbase + (size_t)(chunk*16 + srow)*Kd, &Bs[chunk*512]);
    }
    __syncthreads();                               // vmcnt(0) drained by compiler
    bh8 af[4], bf[4];
    for (int i=0;i<4;i++) af[i] = *(const bh8*)&As[(wr*64 + i*16 + frow)*32 + fk];
    for (int j=0;j<4;j++) bf[j] = *(const bh8*)&Bs[(wc*64 + j*16 + frow)*32 + fk];
    for (int i=0;i<4;i++)
      for (int j=0;j<4;j++)
        acc[i][j] = __builtin_amdgcn_mfma_f32_16x16x32_bf16(af[i], bf[j], acc[i][j], 0, 0, 0);
    __syncthreads();                               // protect LDS for next stage
  }
  const int rb = (lane >> 4) * 4;                  // C/D: col=lane&15, row=(lane>>4)*4+reg
  const int cb = lane & 15;
  for (int i=0;i<4;i++){
    for (int j=0;j<4;j++){
      int lcol = wc*64 + j*16 + cb;
      int col  = bn*128 + lcol;
      for (int r=0;r<4;r++){
        int lrow = wr*64 + i*16 + rb + r;
        size_t row = (size_t)bm*128 + lrow;
        float v = acc[i][j][r];
        if (EPI == 0){
          Cf[row*Nn + col] = v;
        } else if (EPI == 1){
          Cb[row*Nn + col] = f2bf(v + aux0[col]);
        } else if (EPI == 2){
          v += aux0[(row >> 5)*Nn + col];          // + g@w3a^T per group (slice-local)
          v = v*scale[col] + shift[col];           // BN2
          Cb[row*Nn + col] = f2bf(fmaxf(v, 0.f));  // ReLU
        } else {
          short bv = f2bf(v + aux0[col]);
          if (EPI == 3) Cb[row*Nn + col] = bv;     // f2 still needed downstream
          smem[lrow*128 + lcol] = bv;              // stage tile for fused pool
        }
      }
    }
  }
  if (EPI >= 3){
    __syncthreads();                               // tile complete in LDS
    int c = t & 127, gsel = t >> 7;                // 256 thr -> 2 (group,col) each
#pragma unroll
    for (int gg=0; gg<2; gg++){
      int g = gsel*2 + gg;                         // 0..3 within tile
      float mx = -3.4e38f;
#pragma unroll
      for (int k=0;k<PK;k++) mx = fmaxf(mx, bf2f(smem[(g*32 + k)*128 + c]));
      size_t grow = (size_t)bm*4 + g;
      int gcol = bn*128 + c;
      if (EPI == 3) pool_bf[grow*256  + gcol] = f2bf(mx);
      else          pool_f [grow*PTOK + gcol] = mx;
    }
  }
}

// ---------------- 0. weight conversion + BN folding ----------------
__global__ __launch_bounds__(256) void prep_kernel(const float* __restrict__ w2,
    const float* __restrict__ w3, const float* __restrict__ w4,
    const float* __restrict__ g1, const float* __restrict__ be1,
    const float* __restrict__ mu1, const float* __restrict__ va1,
    const float* __restrict__ g2, const float* __restrict__ be2,
    const float* __restrict__ mu2, const float* __restrict__ va2,
    short* __restrict__ w2b, short* __restrict__ w3ab, short* __restrict__ w3bb,
    short* __restrict__ w4b, float* __restrict__ sc1, float* __restrict__ sh1,
    float* __restrict__ sc2, float* __restrict__ sh2){
  int i = blockIdx.x*256 + threadIdx.x;
  if (i < 256*128) w2b[i] = f2bf(w2[i]);
  if (i < 512*512){
    int f = i >> 9, e = i & 511;
    short v = f2bf(w3[i]);
    if (e < 256) w3ab[f*256 + e] = v; else w3bb[f*256 + (e-256)] = v;
  }
  if (i < 384*512) w4b[i] = f2bf(w4[i]);
  if (i < 128){ float s = g1[i]*rsqrtf(va1[i] + BN_EPS_C); sc1[i]=s; sh1[i]=be1[i]-mu1[i]*s; }
  if (i < 512){ float s = g2[i]*rsqrtf(va2[i] + BN_EPS_C); sc2[i]=s; sh2[i]=be2[i]-mu2[i]*s; }
}

// ---------------- launcher ----------------
extern "C" void kernel_launch(void* const* d_in, const int* in_sizes, int n_in,
                              void* d_out, int out_size, void* d_ws, size_t ws_size,
                              hipStream_t stream){
  const float* points = (const float*)d_in[0];
  const float* w1  = (const float*)d_in[1];
  const float* g1  = (const float*)d_in[2];
  const float* be1 = (const float*)d_in[3];
  const float* mu1 = (const float*)d_in[4];
  const float* va1 = (const float*)d_in[5];
  const float* w2  = (const float*)d_in[6];
  const float* b2  = (const float*)d_in[7];
  const float* w3  = (const float*)d_in[8];
  const float* g2  = (const float*)d_in[9];
  const float* be2 = (const float*)d_in[10];
  const float* mu2 = (const float*)d_in[11];
  const float* va2 = (const float*)d_in[12];
  const float* w4  = (const float*)d_in[13];
  const float* b4  = (const float*)d_in[14];
  float* tokens  = (float*)d_out;                       // [PM, 384]
  float* centers = (float*)d_out + (size_t)PM*PTOK;     // [PM, 3]

  // ---- fixed workspace region (~25.1 MB) ----
  char* ws = (char*)d_ws;
  float* grp  = (float*)(ws + 0);              // 262144x3 fp32  = 3 MB
  short* gbuf = (short*)(ws + 3145728ull);     // 8192x256 bf16  = 4 MB
  float* Hbuf = (float*)(ws + 7340032ull);     // 8192x512 fp32  = 16 MB
  short* w2b  = (short*)(ws + 24117248ull);    // 256x128 bf16
  short* w3ab = (short*)(ws + 24182784ull);    // 512x256 bf16
  short* w3bb = (short*)(ws + 24444928ull);    // 512x256 bf16
  short* w4b  = (short*)(ws + 24707072ull);    // 384x512 bf16
  float* sc1  = (float*)(ws + 25100288ull);
  float* sh1  = (float*)(ws + 25100800ull);
  float* sc2  = (float*)(ws + 25101312ull);
  float* sh2  = (float*)(ws + 25103360ull);
  const size_t sliceBase = 25105408ull;

  // ---- adaptive row-slicing: peak slice use = 1792 bytes/row ----
  size_t avail = (ws_size > sliceBase) ? (ws_size - sliceBase) : 0;
  long long smax = (long long)(avail / 1792u);
  int S = (int)((smax / 4096) * 4096);
  if (S > PMK) S = PMK;
  if (S < 4096) S = 4096;   // below ~32 MB ws nothing fits; best effort
  char* sl = ws + sliceBase;

  prep_kernel<<<1024, 256, 0, stream>>>(w2, w3, w4, g1, be1, mu1, va1, g2, be2, mu2, va2,
                                        w2b, w3ab, w3bb, w4b, sc1, sh1, sc2, sh2);
  fps_kernel<<<PB, 1024, 0, stream>>>(points, centers);
  knn_kernel<<<PM, 256, 0, stream>>>(points, centers, grp);

  for (int r0 = 0; r0 < PMK; r0 += S){
    int rows = (PMK - r0 < S) ? (PMK - r0) : S;    // multiple of 4096
    int g0 = r0 >> 5, ng = rows >> 5;              // groups in slice
    short* f1 = (short*)(sl + 0);                  // rows x 128 bf16
    short* f2 = (short*)(sl + (size_t)S*256);      // rows x 256 bf16
    short* f3 = (short*)(sl + (size_t)S*768);      // rows x 512 bf16

    layer1_kernel<<<(rows*128)/256, 256, 0, stream>>>(grp + (size_t)r0*3, w1, sc1, sh1, f1);
    // f2 = f1 @ w2^T + b2, fused g = maxpool_k(f2)
    gemm_bt<3><<<dim3(rows/128, 2), 256, 0, stream>>>(f1, w2b, nullptr, f2, 256, 128,
                                                      b2, nullptr, nullptr,
                                                      gbuf + (size_t)g0*256, nullptr);
    // H = g @ w3[:, :256]^T   (per-group part of the concat GEMM)
    gemm_bt<0><<<dim3(ng/128, 4), 256, 0, stream>>>(gbuf + (size_t)g0*256, w3ab,
                                                    Hbuf + (size_t)g0*512, nullptr, 512, 256,
                                                    nullptr, nullptr, nullptr, nullptr, nullptr);
    // f3 = relu(bn2(f2 @ w3[:, 256:]^T + H[group]))
    gemm_bt<2><<<dim3(rows/128, 4), 256, 0, stream>>>(f2, w3bb, nullptr, f3, 512, 256,
                                                      Hbuf + (size_t)g0*512, sc2, sh2,
                                                      nullptr, nullptr);
    // tokens = maxpool_k(f3 @ w4^T + b4), f4 never materialized
    gemm_bt<4><<<dim3(rows/128, 3), 256, 0, stream>>>(f3, w4b, nullptr, nullptr, 384, 512,
                                                      b4, nullptr, nullptr,
                                                      nullptr, tokens + (size_t)g0*384);
  }
}

// Round 9
// 1474.070 us; speedup vs baseline: 1.1983x; 1.0057x over previous
//
#include <hip/hip_runtime.h>
#include <stdint.h>

// ---------------- problem constants ----------------
#define PB 16            // batches
#define PN 8192          // points per batch
#define PG 512           // FPS samples (centers) per batch
#define PK 32            // knn group size
#define PTOK 384
#define PM (PB*PG)       // 8192 groups total
#define PMK (PM*PK)      // 262144 MLP rows
static constexpr float BN_EPS_C = 1e-5f;

typedef short bh8  __attribute__((ext_vector_type(8)));
typedef float f32x4 __attribute__((ext_vector_type(4)));

__device__ __forceinline__ short f2bf(float f){
  unsigned u = __float_as_uint(f);
  unsigned r = u + 0x7fffu + ((u>>16)&1u);   // RNE
  return (short)(r>>16);
}
__device__ __forceinline__ float bf2f(short s){
  return __uint_as_float(((unsigned)(unsigned short)s)<<16);
}
__device__ __forceinline__ void gload16(const void* g, void* l){
  __builtin_amdgcn_global_load_lds((const __attribute__((address_space(1))) unsigned int*)g,
                                   (__attribute__((address_space(3))) unsigned int*)l,
                                   16, 0, 0);
}

// ---------------- 1. FPS: 1024 thr/batch, ONE barrier/round --------------------
// u64 key = (bits(md)<<32)|(PN-1-j): u64 max == numpy argmax (first-index ties;
// semantics identical to the R5/R7-passing kernel). Cross-wave reduce collapsed
// into a single LDS u64 atomicMax by each wave's lane0 (16 pipelined same-addr
// DS atomics), then one barrier + one broadcast b64 read. Coords packed float4
// => one ds_read_b128 for the winner. Triple-buffered slot: reset of slot g+1
// (pre-barrier, round g) vs its last read (post-barrier, round g-2) is
// separated by barrier g-1; atomics vs reset separated by barrier g-1.
__global__ __launch_bounds__(1024, 4) void fps_kernel(const float* __restrict__ points,
                                                      float* __restrict__ centers){
#pragma clang fp contract(off)
  const int b = blockIdx.x;
  const int t = threadIdx.x;
  const float* P = points + (size_t)b*PN*3;
  __shared__ float4 Lc[PN];                        // 128 KB coord mirror
  __shared__ unsigned long long swa[3];
  float px[8], py[8], pz[8], md[8];
#pragma unroll
  for (int i=0;i<8;i++){
    int j = i*1024 + t;
    float x=P[j*3+0], y=P[j*3+1], z=P[j*3+2];
    px[i]=x; py[i]=y; pz[i]=z; md[i]=1e10f;
    Lc[j] = make_float4(x,y,z,0.f);
  }
  if (t<3) swa[t] = 0ull;
  float cx=P[0], cy=P[1], cz=P[2];                 // start index 0
  if (t==0){ float* c = centers + (size_t)b*PG*3; c[0]=cx; c[1]=cy; c[2]=cz; }
  const int lane = t & 63;
  __syncthreads();
  for (int g=1; g<PG; g++){
    const int sl = g%3, ns = (g+1)%3;
    float bv=-1.0f; int bi=0;
#pragma unroll
    for (int i=0;i<8;i++){
      float dx=px[i]-cx, dy=py[i]-cy, dz=pz[i]-cz;
      float d2 = (dx*dx + dy*dy) + dz*dz;          // numpy order, no fma
      md[i] = fminf(md[i], d2);
      if (md[i] > bv){ bv = md[i]; bi = i*1024 + t; }   // ascending i => lowest idx on tie
    }
    unsigned long long bk = ((unsigned long long)__float_as_uint(bv)<<32)
                          | (unsigned)(PN-1 - bi);
#pragma unroll
    for (int off=32; off; off>>=1){
      unsigned long long o = __shfl_down(bk, off);
      if (o > bk) bk = o;
    }
    if (lane==0) atomicMax(&swa[sl], bk);          // 16 pipelined DS atomics
    if (t==0) swa[ns] = 0ull;                      // reset future slot (safe: see hdr)
    __syncthreads();                               // the only barrier per round
    unsigned long long w = swa[sl];                // broadcast b64 read
    int j = PN-1 - (int)(w & 0xFFFFFFFFu);
    float4 c = Lc[j];                              // one ds_read_b128
    cx = c.x; cy = c.y; cz = c.z;
    if (t==0){ float* cc = centers + ((size_t)b*PG + g)*3; cc[0]=cx; cc[1]=cy; cc[2]=cz; }
  }
}

// ---------------- 2. KNN: exact top-32, incremental lmin + owner rescan --------
__global__ __launch_bounds__(256) void knn_kernel(const float* __restrict__ points,
                                                  const float* __restrict__ centers,
                                                  float* __restrict__ groups){
#pragma clang fp contract(off)
  const int m = blockIdx.x;
  const int b = m >> 9;       // m / PG
  const int t = threadIdx.x;
  const float* P = points + (size_t)b*PN*3;
  const float* c = centers + (size_t)m*3;
  const float cx=c[0], cy=c[1], cz=c[2];
  const float cn = (cx*cx + cy*cy) + cz*cz;
  unsigned long long key[PK];
#pragma unroll
  for (int i=0;i<PK;i++){
    int j = i*256 + t;
    float x=P[j*3+0], y=P[j*3+1], z=P[j*3+2];
    float pn = (x*x + y*y) + z*z;
    float e  = (cx*x + cy*y) + cz*z;
    float d2 = (cn + pn) - 2.0f*e;                 // reference formula
    unsigned u = __float_as_uint(d2);
    u ^= (u & 0x80000000u) ? 0xFFFFFFFFu : 0x80000000u;   // total order
    key[i] = ((unsigned long long)u << 32) | (unsigned)j;
  }
  unsigned long long lmin = key[0];
#pragma unroll
  for (int i=1;i<PK;i++) if (key[i] < lmin) lmin = key[i];
  __shared__ unsigned long long swk[2][4];
  __shared__ int s_idx[PK];
  const int lane = t & 63, wid = t >> 6;
  for (int it=0; it<PK; it++){
    unsigned long long v = lmin;
#pragma unroll
    for (int off=32; off; off>>=1){
      unsigned long long o = __shfl_down(v, off);
      if (o < v) v = o;
    }
    if (lane==0) swk[it&1][wid] = v;
    __syncthreads();                               // the only barrier per round
    unsigned long long w = swk[it&1][0];
#pragma unroll
    for (int q=1;q<4;q++) if (swk[it&1][q] < w) w = swk[it&1][q];
    int wj = (int)(w & 0xFFFFFFFFull);
    if (t==0) s_idx[it] = wj;
    if ((wj & 255) == t){                          // owner-only knockout + rescan
#pragma unroll
      for (int i=0;i<PK;i++) if (key[i] == w) key[i] = ~0ull;
      lmin = key[0];
#pragma unroll
      for (int i=1;i<PK;i++) if (key[i] < lmin) lmin = key[i];
    }
  }
  __syncthreads();
  if (t < PK*3){
    int k = t/3, cc = t - k*3;
    int j = s_idx[k];
    groups[((size_t)m*PK + k)*3 + cc] = P[j*3+cc] - c[cc];
  }
}

// ---------------- 3. layer1: 3->128 linear + BN1 + ReLU, fp32 VALU ----------------
__global__ __launch_bounds__(256) void layer1_kernel(const float* __restrict__ groups,
                                                     const float* __restrict__ w1,
                                                     const float* __restrict__ sc1,
                                                     const float* __restrict__ sh1,
                                                     short* __restrict__ f1){
  int idx = blockIdx.x*256 + threadIdx.x;   // [mk, d], d fastest (slice-local)
  int d  = idx & 127;
  int mk = idx >> 7;
  const float* x = groups + (size_t)mk*3;
  float a = x[0]*w1[d*3+0] + x[1]*w1[d*3+1] + x[2]*w1[d*3+2];
  float y = a*sc1[d] + sh1[d];
  f1[idx] = f2bf(fmaxf(y, 0.f));
}

// ---------------- 4. bf16 MFMA GEMM: C[M,N] = A[M,K] @ B[N,K]^T ----------------
// grid = (bn, bm): bn fastest => blocks sharing an A-tile are dispatch-adjacent
// (A-tile re-fetch hits warm L2/L3).
// EPI 0: store fp32 raw (H).
// EPI 1: +bias[col], store bf16.
// EPI 2: relu(bn2(acc+H[row/32])), store bf16.
// EPI 3: +bias, store bf16 AND fused k-maxpool -> pool_bf (128 rows = 4 groups).
// EPI 4: +bias, fused k-maxpool only -> pool_f (f4 never materialized).
template<int EPI>
__global__ __launch_bounds__(256) void gemm_bt(const short* __restrict__ A,
                                               const short* __restrict__ Bw,
                                               float* __restrict__ Cf,
                                               short* __restrict__ Cb,
                                               int Nn, int Kd,
                                               const float* __restrict__ aux0,
                                               const float* __restrict__ scale,
                                               const float* __restrict__ shift,
                                               short* __restrict__ pool_bf,
                                               float* __restrict__ pool_f){
  __shared__ __align__(16) short smem[(EPI>=3) ? 16384 : 8192];   // 32 KB / 16 KB
  short* As = smem;
  short* Bs = smem + 4096;
  const int bm = blockIdx.y, bn = blockIdx.x;      // bn fastest (A-tile adjacency)
  const int t = threadIdx.x;
  const int lane = t & 63, wid = t >> 6;
  const int wr = wid >> 1, wc = wid & 1;          // 2x2 waves, each 64x64
  f32x4 acc[4][4] = {};
  const int srow = lane >> 2;                      // staging: row within 16-row chunk
  const int scol = (lane & 3) * 8;                 // staging: 8-elem column offset
  const int frow = lane & 15;                      // fragment row/col
  const int fk   = (lane >> 4) * 8;                // fragment k offset
  for (int k0 = 0; k0 < Kd; k0 += 32){
    const size_t abase = ((size_t)bm*128) * Kd + k0 + scol;
    const size_t bbase = ((size_t)bn*128) * Kd + k0 + scol;
    for (int q=0;q<2;q++){
      int chunk = wid*2 + q;                       // 8 chunks x 16 rows = 128 rows
      gload16(A  + abase + (size_t)(chunk*16 + srow)*Kd, &As[chunk*512]);
      gload16(Bw + bbase + (size_t)(chunk*16 + srow)*Kd, &Bs[chunk*512]);
    }
    __syncthreads();                               // vmcnt(0) drained by compiler
    bh8 af[4], bf[4];
    for (int i=0;i<4;i++) af[i] = *(const bh8*)&As[(wr*64 + i*16 + frow)*32 + fk];
    for (int j=0;j<4;j++) bf[j] = *(const bh8*)&Bs[(wc*64 + j*16 + frow)*32 + fk];
    for (int i=0;i<4;i++)
      for (int j=0;j<4;j++)
        acc[i][j] = __builtin_amdgcn_mfma_f32_16x16x32_bf16(af[i], bf[j], acc[i][j], 0, 0, 0);
    __syncthreads();                               // protect LDS for next stage
  }
  const int rb = (lane >> 4) * 4;                  // C/D: col=lane&15, row=(lane>>4)*4+reg
  const int cb = lane & 15;
  for (int i=0;i<4;i++){
    for (int j=0;j<4;j++){
      int lcol = wc*64 + j*16 + cb;
      int col  = bn*128 + lcol;
      for (int r=0;r<4;r++){
        int lrow = wr*64 + i*16 + rb + r;
        size_t row = (size_t)bm*128 + lrow;
        float v = acc[i][j][r];
        if (EPI == 0){
          Cf[row*Nn + col] = v;
        } else if (EPI == 1){
          Cb[row*Nn + col] = f2bf(v + aux0[col]);
        } else if (EPI == 2){
          v += aux0[(row >> 5)*Nn + col];          // + g@w3a^T per group (slice-local)
          v = v*scale[col] + shift[col];           // BN2
          Cb[row*Nn + col] = f2bf(fmaxf(v, 0.f));  // ReLU
        } else {
          short bv = f2bf(v + aux0[col]);
          if (EPI == 3) Cb[row*Nn + col] = bv;     // f2 still needed downstream
          smem[lrow*128 + lcol] = bv;              // stage tile for fused pool
        }
      }
    }
  }
  if (EPI >= 3){
    __syncthreads();                               // tile complete in LDS
    int c = t & 127, gsel = t >> 7;                // 256 thr -> 2 (group,col) each
#pragma unroll
    for (int gg=0; gg<2; gg++){
      int g = gsel*2 + gg;                         // 0..3 within tile
      float mx = -3.4e38f;
#pragma unroll
      for (int k=0;k<PK;k++) mx = fmaxf(mx, bf2f(smem[(g*32 + k)*128 + c]));
      size_t grow = (size_t)bm*4 + g;
      int gcol = bn*128 + c;
      if (EPI == 3) pool_bf[grow*256  + gcol] = f2bf(mx);
      else          pool_f [grow*PTOK + gcol] = mx;
    }
  }
}

// ---------------- 0. weight conversion + BN folding ----------------
__global__ __launch_bounds__(256) void prep_kernel(const float* __restrict__ w2,
    const float* __restrict__ w3, const float* __restrict__ w4,
    const float* __restrict__ g1, const float* __restrict__ be1,
    const float* __restrict__ mu1, const float* __restrict__ va1,
    const float* __restrict__ g2, const float* __restrict__ be2,
    const float* __restrict__ mu2, const float* __restrict__ va2,
    short* __restrict__ w2b, short* __restrict__ w3ab, short* __restrict__ w3bb,
    short* __restrict__ w4b, float* __restrict__ sc1, float* __restrict__ sh1,
    float* __restrict__ sc2, float* __restrict__ sh2){
  int i = blockIdx.x*256 + threadIdx.x;
  if (i < 256*128) w2b[i] = f2bf(w2[i]);
  if (i < 512*512){
    int f = i >> 9, e = i & 511;
    short v = f2bf(w3[i]);
    if (e < 256) w3ab[f*256 + e] = v; else w3bb[f*256 + (e-256)] = v;
  }
  if (i < 384*512) w4b[i] = f2bf(w4[i]);
  if (i < 128){ float s = g1[i]*rsqrtf(va1[i] + BN_EPS_C); sc1[i]=s; sh1[i]=be1[i]-mu1[i]*s; }
  if (i < 512){ float s = g2[i]*rsqrtf(va2[i] + BN_EPS_C); sc2[i]=s; sh2[i]=be2[i]-mu2[i]*s; }
}

// ---------------- launcher ----------------
extern "C" void kernel_launch(void* const* d_in, const int* in_sizes, int n_in,
                              void* d_out, int out_size, void* d_ws, size_t ws_size,
                              hipStream_t stream){
  const float* points = (const float*)d_in[0];
  const float* w1  = (const float*)d_in[1];
  const float* g1  = (const float*)d_in[2];
  const float* be1 = (const float*)d_in[3];
  const float* mu1 = (const float*)d_in[4];
  const float* va1 = (const float*)d_in[5];
  const float* w2  = (const float*)d_in[6];
  const float* b2  = (const float*)d_in[7];
  const float* w3  = (const float*)d_in[8];
  const float* g2  = (const float*)d_in[9];
  const float* be2 = (const float*)d_in[10];
  const float* mu2 = (const float*)d_in[11];
  const float* va2 = (const float*)d_in[12];
  const float* w4  = (const float*)d_in[13];
  const float* b4  = (const float*)d_in[14];
  float* tokens  = (float*)d_out;                       // [PM, 384]
  float* centers = (float*)d_out + (size_t)PM*PTOK;     // [PM, 3]

  // ---- fixed workspace region (~25.1 MB) ----
  char* ws = (char*)d_ws;
  float* grp  = (float*)(ws + 0);              // 262144x3 fp32  = 3 MB
  short* gbuf = (short*)(ws + 3145728ull);     // 8192x256 bf16  = 4 MB
  float* Hbuf = (float*)(ws + 7340032ull);     // 8192x512 fp32  = 16 MB
  short* w2b  = (short*)(ws + 24117248ull);    // 256x128 bf16
  short* w3ab = (short*)(ws + 24182784ull);    // 512x256 bf16
  short* w3bb = (short*)(ws + 24444928ull);    // 512x256 bf16
  short* w4b  = (short*)(ws + 24707072ull);    // 384x512 bf16
  float* sc1  = (float*)(ws + 25100288ull);
  float* sh1  = (float*)(ws + 25100800ull);
  float* sc2  = (float*)(ws + 25101312ull);
  float* sh2  = (float*)(ws + 25103360ull);
  const size_t sliceBase = 25105408ull;

  // ---- adaptive row-slicing: peak slice use = 1792 bytes/row ----
  size_t avail = (ws_size > sliceBase) ? (ws_size - sliceBase) : 0;
  long long smax = (long long)(avail / 1792u);
  int S = (int)((smax / 4096) * 4096);
  if (S > PMK) S = PMK;
  if (S < 4096) S = 4096;   // below ~32 MB ws nothing fits; best effort
  char* sl = ws + sliceBase;

  prep_kernel<<<1024, 256, 0, stream>>>(w2, w3, w4, g1, be1, mu1, va1, g2, be2, mu2, va2,
                                        w2b, w3ab, w3bb, w4b, sc1, sh1, sc2, sh2);
  fps_kernel<<<PB, 1024, 0, stream>>>(points, centers);
  knn_kernel<<<PM, 256, 0, stream>>>(points, centers, grp);

  for (int r0 = 0; r0 < PMK; r0 += S){
    int rows = (PMK - r0 < S) ? (PMK - r0) : S;    // multiple of 4096
    int g0 = r0 >> 5, ng = rows >> 5;              // groups in slice
    short* f1 = (short*)(sl + 0);                  // rows x 128 bf16
    short* f2 = (short*)(sl + (size_t)S*256);      // rows x 256 bf16
    short* f3 = (short*)(sl + (size_t)S*768);      // rows x 512 bf16

    layer1_kernel<<<(rows*128)/256, 256, 0, stream>>>(grp + (size_t)r0*3, w1, sc1, sh1, f1);
    // f2 = f1 @ w2^T + b2, fused g = maxpool_k(f2)
    gemm_bt<3><<<dim3(2, rows/128), 256, 0, stream>>>(f1, w2b, nullptr, f2, 256, 128,
                                                      b2, nullptr, nullptr,
                                                      gbuf + (size_t)g0*256, nullptr);
    // H = g @ w3[:, :256]^T   (per-group part of the concat GEMM)
    gemm_bt<0><<<dim3(4, ng/128), 256, 0, stream>>>(gbuf + (size_t)g0*256, w3ab,
                                                    Hbuf + (size_t)g0*512, nullptr, 512, 256,
                                                    nullptr, nullptr, nullptr, nullptr, nullptr);
    // f3 = relu(bn2(f2 @ w3[:, 256:]^T + H[group]))
    gemm_bt<2><<<dim3(4, rows/128), 256, 0, stream>>>(f2, w3bb, nullptr, f3, 512, 256,
                                                      Hbuf + (size_t)g0*512, sc2, sh2,
                                                      nullptr, nullptr);
    // tokens = maxpool_k(f3 @ w4^T + b4), f4 never materialized
    gemm_bt<4><<<dim3(3, rows/128), 256, 0, stream>>>(f3, w4b, nullptr, nullptr, 384, 512,
                                                      b4, nullptr, nullptr,
                                                      nullptr, tokens + (size_t)g0*384);
  }
}

// Round 10
// 1356.838 us; speedup vs baseline: 1.3018x; 1.0864x over previous
//
#include <hip/hip_runtime.h>
#include <stdint.h>

// ---------------- problem constants ----------------
#define PB 16            // batches
#define PN 8192          // points per batch
#define PG 512           // FPS samples (centers) per batch
#define PK 32            // knn group size
#define PTOK 384
#define PM (PB*PG)       // 8192 groups total
#define PMK (PM*PK)      // 262144 MLP rows
static constexpr float BN_EPS_C = 1e-5f;

typedef short bh8  __attribute__((ext_vector_type(8)));
typedef float f32x4 __attribute__((ext_vector_type(4)));

__device__ __forceinline__ short f2bf(float f){
  unsigned u = __float_as_uint(f);
  unsigned r = u + 0x7fffu + ((u>>16)&1u);   // RNE
  return (short)(r>>16);
}
__device__ __forceinline__ float bf2f(short s){
  return __uint_as_float(((unsigned)(unsigned short)s)<<16);
}
__device__ __forceinline__ void gload16(const void* g, void* l){
  __builtin_amdgcn_global_load_lds((const __attribute__((address_space(1))) unsigned int*)g,
                                   (__attribute__((address_space(3))) unsigned int*)l,
                                   16, 0, 0);
}

// ---------------- 1. FPS: spatially-pruned, EXACT ------------------------------
// md[i]=min(md[i],d2) is a provable no-op for a wave's 512 points when
// dmin2(waveBBox, c) >= max md over the wave => skip update+butterfly, reuse the
// stored wave candidate key (unchanged). Conservative *0.999999 on the bound
// makes its rounding harmless; md values stay bit-identical to the unpruned
// kernel. Key=(bits(md)<<32)|(8191-origj): u64 max == numpy first-index argmax,
// permutation-invariant. Morton counting-sort (init-only) gives each wave a
// spatially compact point set; cell choice affects only skip RATE, never values.
// Reduce structure = R9 (passing): lane0 atomicMax into slot, 1 barrier/round,
// triple-buffered slot reset (races separated by barrier g-1; analyzed R9).
__global__ __launch_bounds__(1024, 4) void fps_kernel(const float* __restrict__ points,
                                                      float* __restrict__ centers){
#pragma clang fp contract(off)
  const int b = blockIdx.x;
  const int t = threadIdx.x;
  const float* P = points + (size_t)b*PN*3;
  __shared__ float Lx[PN], Ly[PN], Lz[PN];         // 96 KB coord mirror (ORIG index)
  __shared__ unsigned short sidx[PN];              // 16 KB sorted->orig
  __shared__ int shist[64];
  __shared__ unsigned long long swa[3];
  if (t < 64) shist[t] = 0;
  if (t < 3)  swa[t] = 0ull;
  __syncthreads();
  // pass 1: load + mirror + 6-bit Morton histogram (fixed [-4,4]^3 box)
  int mycell[8];
#pragma unroll
  for (int i=0;i<8;i++){
    int j = i*1024 + t;
    float x=P[j*3+0], y=P[j*3+1], z=P[j*3+2];
    Lx[j]=x; Ly[j]=y; Lz[j]=z;
    int qx=(int)fminf(fmaxf((x+4.f)*0.5f,0.f),3.f);
    int qy=(int)fminf(fmaxf((y+4.f)*0.5f,0.f),3.f);
    int qz=(int)fminf(fmaxf((z+4.f)*0.5f,0.f),3.f);
    int mc=(qx&1)|((qy&1)<<1)|((qz&1)<<2)|((qx>>1)<<3)|((qy>>1)<<4)|((qz>>1)<<5);
    mycell[i]=mc;
    atomicAdd(&shist[mc],1);
  }
  __syncthreads();
  if (t==0){ int acc=0; for (int k=0;k<64;k++){ int h=shist[k]; shist[k]=acc; acc+=h; } }
  __syncthreads();
  // pass 2: scatter ranks (order within cell nondeterministic — values unaffected)
#pragma unroll
  for (int i=0;i<8;i++){
    int j = i*1024 + t;
    int r = atomicAdd(&shist[mycell[i]],1);
    sidx[r] = (unsigned short)j;
  }
  __syncthreads();
  // pass 3: gather sorted ownership (thread t: sorted slots [8t,8t+8)) + wave bbox
  float px[8],py[8],pz[8],md[8]; int lowc[8];
  float tlx=1e30f,tly=1e30f,tlz=1e30f,thx=-1e30f,thy=-1e30f,thz=-1e30f;
#pragma unroll
  for (int i=0;i<8;i++){
    int oj = sidx[t*8+i];
    float x=Lx[oj], y=Ly[oj], z=Lz[oj];
    px[i]=x; py[i]=y; pz[i]=z; md[i]=1e10f; lowc[i]=PN-1-oj;
    tlx=fminf(tlx,x); thx=fmaxf(thx,x);
    tly=fminf(tly,y); thy=fmaxf(thy,y);
    tlz=fminf(tlz,z); thz=fmaxf(thz,z);
  }
#pragma unroll
  for (int off=32; off; off>>=1){
    tlx=fminf(tlx,__shfl_xor(tlx,off)); thx=fmaxf(thx,__shfl_xor(thx,off));
    tly=fminf(tly,__shfl_xor(tly,off)); thy=fmaxf(thy,__shfl_xor(thy,off));
    tlz=fminf(tlz,__shfl_xor(tlz,off)); thz=fmaxf(thz,__shfl_xor(thz,off));
  }
  unsigned long long wkey = ((unsigned long long)0x7F800000u)<<32;  // wb=+inf: no skip before 1st store
  float cx=Lx[0], cy=Ly[0], cz=Lz[0];              // start = orig point 0
  if (t==0){ float* c = centers + (size_t)b*PG*3; c[0]=cx; c[1]=cy; c[2]=cz; }
  const int lane = t & 63;
  __syncthreads();
  for (int g=1; g<PG; g++){
    const int sl = g%3, ns = (g+1)%3;
    float ddx=fmaxf(fmaxf(tlx-cx, cx-thx),0.f);    // wave-uniform skip test
    float ddy=fmaxf(fmaxf(tly-cy, cy-thy),0.f);
    float ddz=fmaxf(fmaxf(tlz-cz, cz-thz),0.f);
    float dmin2=((ddx*ddx+ddy*ddy)+ddz*ddz)*0.999999f;   // conservative bound
    if (!(dmin2 >= __uint_as_float((unsigned)(wkey>>32)))){
      unsigned long long bk = 0ull;
#pragma unroll
      for (int i=0;i<8;i++){
        float dx=px[i]-cx, dy=py[i]-cy, dz=pz[i]-cz;
        float d2 = (dx*dx + dy*dy) + dz*dz;        // numpy order, no fma
        md[i] = fminf(md[i], d2);
        unsigned long long ki = ((unsigned long long)__float_as_uint(md[i])<<32)
                              | (unsigned)lowc[i];
        if (ki > bk) bk = ki;
      }
#pragma unroll
      for (int mask=32; mask; mask>>=1){
        unsigned long long o = __shfl_xor(bk, mask);
        if (o > bk) bk = o;
      }
      wkey = bk;                                   // wave max, all lanes
    }
    if (lane==0) atomicMax(&swa[sl], wkey);
    if (t==0) swa[ns] = 0ull;                      // reset future slot (barrier-separated)
    __syncthreads();                               // the only barrier per round
    unsigned long long w = swa[sl];
    int j = PN-1 - (int)(w & 0xFFFFFFFFu);
    cx = Lx[j]; cy = Ly[j]; cz = Lz[j];            // broadcast reads (same addr)
    if (t==0){ float* cc = centers + ((size_t)b*PG + g)*3; cc[0]=cx; cc[1]=cy; cc[2]=cz; }
  }
}

// ---------------- 2. KNN: exact top-32, incremental lmin + owner rescan --------
__global__ __launch_bounds__(256) void knn_kernel(const float* __restrict__ points,
                                                  const float* __restrict__ centers,
                                                  float* __restrict__ groups){
#pragma clang fp contract(off)
  const int m = blockIdx.x;
  const int b = m >> 9;       // m / PG
  const int t = threadIdx.x;
  const float* P = points + (size_t)b*PN*3;
  const float* c = centers + (size_t)m*3;
  const float cx=c[0], cy=c[1], cz=c[2];
  const float cn = (cx*cx + cy*cy) + cz*cz;
  unsigned long long key[PK];
#pragma unroll
  for (int i=0;i<PK;i++){
    int j = i*256 + t;
    float x=P[j*3+0], y=P[j*3+1], z=P[j*3+2];
    float pn = (x*x + y*y) + z*z;
    float e  = (cx*x + cy*y) + cz*z;
    float d2 = (cn + pn) - 2.0f*e;                 // reference formula
    unsigned u = __float_as_uint(d2);
    u ^= (u & 0x80000000u) ? 0xFFFFFFFFu : 0x80000000u;   // total order
    key[i] = ((unsigned long long)u << 32) | (unsigned)j;
  }
  unsigned long long lmin = key[0];
#pragma unroll
  for (int i=1;i<PK;i++) if (key[i] < lmin) lmin = key[i];
  __shared__ unsigned long long swk[2][4];
  __shared__ int s_idx[PK];
  const int lane = t & 63, wid = t >> 6;
  for (int it=0; it<PK; it++){
    unsigned long long v = lmin;
#pragma unroll
    for (int off=32; off; off>>=1){
      unsigned long long o = __shfl_down(v, off);
      if (o < v) v = o;
    }
    if (lane==0) swk[it&1][wid] = v;
    __syncthreads();                               // the only barrier per round
    unsigned long long w = swk[it&1][0];
#pragma unroll
    for (int q=1;q<4;q++) if (swk[it&1][q] < w) w = swk[it&1][q];
    int wj = (int)(w & 0xFFFFFFFFull);
    if (t==0) s_idx[it] = wj;
    if ((wj & 255) == t){                          // owner-only knockout + rescan
#pragma unroll
      for (int i=0;i<PK;i++) if (key[i] == w) key[i] = ~0ull;
      lmin = key[0];
#pragma unroll
      for (int i=1;i<PK;i++) if (key[i] < lmin) lmin = key[i];
    }
  }
  __syncthreads();
  if (t < PK*3){
    int k = t/3, cc = t - k*3;
    int j = s_idx[k];
    groups[((size_t)m*PK + k)*3 + cc] = P[j*3+cc] - c[cc];
  }
}

// ---------------- 3. layer1: 3->128 linear + BN1 + ReLU, fp32 VALU ----------------
__global__ __launch_bounds__(256) void layer1_kernel(const float* __restrict__ groups,
                                                     const float* __restrict__ w1,
                                                     const float* __restrict__ sc1,
                                                     const float* __restrict__ sh1,
                                                     short* __restrict__ f1){
  int idx = blockIdx.x*256 + threadIdx.x;   // [mk, d], d fastest (slice-local)
  int d  = idx & 127;
  int mk = idx >> 7;
  const float* x = groups + (size_t)mk*3;
  float a = x[0]*w1[d*3+0] + x[1]*w1[d*3+1] + x[2]*w1[d*3+2];
  float y = a*sc1[d] + sh1[d];
  f1[idx] = f2bf(fmaxf(y, 0.f));
}

// ---------------- 4. bf16 MFMA GEMM: C[M,N] = A[M,K] @ B[N,K]^T ----------------
// grid = (bn, bm): bn fastest => blocks sharing an A-tile are dispatch-adjacent.
// EPI 0: store fp32 raw (H).
// EPI 1: +bias[col], store bf16.
// EPI 2: relu(bn2(acc+H[row/32])), store bf16.
// EPI 3: +bias, store bf16 AND fused k-maxpool -> pool_bf (128 rows = 4 groups).
// EPI 4: +bias, fused k-maxpool only -> pool_f (f4 never materialized).
template<int EPI>
__global__ __launch_bounds__(256) void gemm_bt(const short* __restrict__ A,
                                               const short* __restrict__ Bw,
                                               float* __restrict__ Cf,
                                               short* __restrict__ Cb,
                                               int Nn, int Kd,
                                               const float* __restrict__ aux0,
                                               const float* __restrict__ scale,
                                               const float* __restrict__ shift,
                                               short* __restrict__ pool_bf,
                                               float* __restrict__ pool_f){
  __shared__ __align__(16) short smem[(EPI>=3) ? 16384 : 8192];   // 32 KB / 16 KB
  short* As = smem;
  short* Bs = smem + 4096;
  const int bm = blockIdx.y, bn = blockIdx.x;      // bn fastest (A-tile adjacency)
  const int t = threadIdx.x;
  const int lane = t & 63, wid = t >> 6;
  const int wr = wid >> 1, wc = wid & 1;          // 2x2 waves, each 64x64
  f32x4 acc[4][4] = {};
  const int srow = lane >> 2;                      // staging: row within 16-row chunk
  const int scol = (lane & 3) * 8;                 // staging: 8-elem column offset
  const int frow = lane & 15;                      // fragment row/col
  const int fk   = (lane >> 4) * 8;                // fragment k offset
  for (int k0 = 0; k0 < Kd; k0 += 32){
    const size_t abase = ((size_t)bm*128) * Kd + k0 + scol;
    const size_t bbase = ((size_t)bn*128) * Kd + k0 + scol;
    for (int q=0;q<2;q++){
      int chunk = wid*2 + q;                       // 8 chunks x 16 rows = 128 rows
      gload16(A  + abase + (size_t)(chunk*16 + srow)*Kd, &As[chunk*512]);
      gload16(Bw + bbase + (size_t)(chunk*16 + srow)*Kd, &Bs[chunk*512]);
    }
    __syncthreads();                               // vmcnt(0) drained by compiler
    bh8 af[4], bf[4];
    for (int i=0;i<4;i++) af[i] = *(const bh8*)&As[(wr*64 + i*16 + frow)*32 + fk];
    for (int j=0;j<4;j++) bf[j] = *(const bh8*)&Bs[(wc*64 + j*16 + frow)*32 + fk];
    for (int i=0;i<4;i++)
      for (int j=0;j<4;j++)
        acc[i][j] = __builtin_amdgcn_mfma_f32_16x16x32_bf16(af[i], bf[j], acc[i][j], 0, 0, 0);
    __syncthreads();                               // protect LDS for next stage
  }
  const int rb = (lane >> 4) * 4;                  // C/D: col=lane&15, row=(lane>>4)*4+reg
  const int cb = lane & 15;
  for (int i=0;i<4;i++){
    for (int j=0;j<4;j++){
      int lcol = wc*64 + j*16 + cb;
      int col  = bn*128 + lcol;
      for (int r=0;r<4;r++){
        int lrow = wr*64 + i*16 + rb + r;
        size_t row = (size_t)bm*128 + lrow;
        float v = acc[i][j][r];
        if (EPI == 0){
          Cf[row*Nn + col] = v;
        } else if (EPI == 1){
          Cb[row*Nn + col] = f2bf(v + aux0[col]);
        } else if (EPI == 2){
          v += aux0[(row >> 5)*Nn + col];          // + g@w3a^T per group (slice-local)
          v = v*scale[col] + shift[col];           // BN2
          Cb[row*Nn + col] = f2bf(fmaxf(v, 0.f));  // ReLU
        } else {
          short bv = f2bf(v + aux0[col]);
          if (EPI == 3) Cb[row*Nn + col] = bv;     // f2 still needed downstream
          smem[lrow*128 + lcol] = bv;              // stage tile for fused pool
        }
      }
    }
  }
  if (EPI >= 3){
    __syncthreads();                               // tile complete in LDS
    int c = t & 127, gsel = t >> 7;                // 256 thr -> 2 (group,col) each
#pragma unroll
    for (int gg=0; gg<2; gg++){
      int g = gsel*2 + gg;                         // 0..3 within tile
      float mx = -3.4e38f;
#pragma unroll
      for (int k=0;k<PK;k++) mx = fmaxf(mx, bf2f(smem[(g*32 + k)*128 + c]));
      size_t grow = (size_t)bm*4 + g;
      int gcol = bn*128 + c;
      if (EPI == 3) pool_bf[grow*256  + gcol] = f2bf(mx);
      else          pool_f [grow*PTOK + gcol] = mx;
    }
  }
}

// ---------------- 0. weight conversion + BN folding ----------------
__global__ __launch_bounds__(256) void prep_kernel(const float* __restrict__ w2,
    const float* __restrict__ w3, const float* __restrict__ w4,
    const float* __restrict__ g1, const float* __restrict__ be1,
    const float* __restrict__ mu1, const float* __restrict__ va1,
    const float* __restrict__ g2, const float* __restrict__ be2,
    const float* __restrict__ mu2, const float* __restrict__ va2,
    short* __restrict__ w2b, short* __restrict__ w3ab, short* __restrict__ w3bb,
    short* __restrict__ w4b, float* __restrict__ sc1, float* __restrict__ sh1,
    float* __restrict__ sc2, float* __restrict__ sh2){
  int i = blockIdx.x*256 + threadIdx.x;
  if (i < 256*128) w2b[i] = f2bf(w2[i]);
  if (i < 512*512){
    int f = i >> 9, e = i & 511;
    short v = f2bf(w3[i]);
    if (e < 256) w3ab[f*256 + e] = v; else w3bb[f*256 + (e-256)] = v;
  }
  if (i < 384*512) w4b[i] = f2bf(w4[i]);
  if (i < 128){ float s = g1[i]*rsqrtf(va1[i] + BN_EPS_C); sc1[i]=s; sh1[i]=be1[i]-mu1[i]*s; }
  if (i < 512){ float s = g2[i]*rsqrtf(va2[i] + BN_EPS_C); sc2[i]=s; sh2[i]=be2[i]-mu2[i]*s; }
}

// ---------------- launcher ----------------
extern "C" void kernel_launch(void* const* d_in, const int* in_sizes, int n_in,
                              void* d_out, int out_size, void* d_ws, size_t ws_size,
                              hipStream_t stream){
  const float* points = (const float*)d_in[0];
  const float* w1  = (const float*)d_in[1];
  const float* g1  = (const float*)d_in[2];
  const float* be1 = (const float*)d_in[3];
  const float* mu1 = (const float*)d_in[4];
  const float* va1 = (const float*)d_in[5];
  const float* w2  = (const float*)d_in[6];
  const float* b2  = (const float*)d_in[7];
  const float* w3  = (const float*)d_in[8];
  const float* g2  = (const float*)d_in[9];
  const float* be2 = (const float*)d_in[10];
  const float* mu2 = (const float*)d_in[11];
  const float* va2 = (const float*)d_in[12];
  const float* w4  = (const float*)d_in[13];
  const float* b4  = (const float*)d_in[14];
  float* tokens  = (float*)d_out;                       // [PM, 384]
  float* centers = (float*)d_out + (size_t)PM*PTOK;     // [PM, 3]

  // ---- fixed workspace region (~25.1 MB) ----
  char* ws = (char*)d_ws;
  float* grp  = (float*)(ws + 0);              // 262144x3 fp32  = 3 MB
  short* gbuf = (short*)(ws + 3145728ull);     // 8192x256 bf16  = 4 MB
  float* Hbuf = (float*)(ws + 7340032ull);     // 8192x512 fp32  = 16 MB
  short* w2b  = (short*)(ws + 24117248ull);    // 256x128 bf16
  short* w3ab = (short*)(ws + 24182784ull);    // 512x256 bf16
  short* w3bb = (short*)(ws + 24444928ull);    // 512x256 bf16
  short* w4b  = (short*)(ws + 24707072ull);    // 384x512 bf16
  float* sc1  = (float*)(ws + 25100288ull);
  float* sh1  = (float*)(ws + 25100800ull);
  float* sc2  = (float*)(ws + 25101312ull);
  float* sh2  = (float*)(ws + 25103360ull);
  const size_t sliceBase = 25105408ull;

  // ---- adaptive row-slicing: peak slice use = 1792 bytes/row ----
  size_t avail = (ws_size > sliceBase) ? (ws_size - sliceBase) : 0;
  long long smax = (long long)(avail / 1792u);
  int S = (int)((smax / 4096) * 4096);
  if (S > PMK) S = PMK;
  if (S < 4096) S = 4096;   // below ~32 MB ws nothing fits; best effort
  char* sl = ws + sliceBase;

  prep_kernel<<<1024, 256, 0, stream>>>(w2, w3, w4, g1, be1, mu1, va1, g2, be2, mu2, va2,
                                        w2b, w3ab, w3bb, w4b, sc1, sh1, sc2, sh2);
  fps_kernel<<<PB, 1024, 0, stream>>>(points, centers);
  knn_kernel<<<PM, 256, 0, stream>>>(points, centers, grp);

  for (int r0 = 0; r0 < PMK; r0 += S){
    int rows = (PMK - r0 < S) ? (PMK - r0) : S;    // multiple of 4096
    int g0 = r0 >> 5, ng = rows >> 5;              // groups in slice
    short* f1 = (short*)(sl + 0);                  // rows x 128 bf16
    short* f2 = (short*)(sl + (size_t)S*256);      // rows x 256 bf16
    short* f3 = (short*)(sl + (size_t)S*768);      // rows x 512 bf16

    layer1_kernel<<<(rows*128)/256, 256, 0, stream>>>(grp + (size_t)r0*3, w1, sc1, sh1, f1);
    // f2 = f1 @ w2^T + b2, fused g = maxpool_k(f2)
    gemm_bt<3><<<dim3(2, rows/128), 256, 0, stream>>>(f1, w2b, nullptr, f2, 256, 128,
                                                      b2, nullptr, nullptr,
                                                      gbuf + (size_t)g0*256, nullptr);
    // H = g @ w3[:, :256]^T   (per-group part of the concat GEMM)
    gemm_bt<0><<<dim3(4, ng/128), 256, 0, stream>>>(gbuf + (size_t)g0*256, w3ab,
                                                    Hbuf + (size_t)g0*512, nullptr, 512, 256,
                                                    nullptr, nullptr, nullptr, nullptr, nullptr);
    // f3 = relu(bn2(f2 @ w3[:, 256:]^T + H[group]))
    gemm_bt<2><<<dim3(4, rows/128), 256, 0, stream>>>(f2, w3bb, nullptr, f3, 512, 256,
                                                      Hbuf + (size_t)g0*512, sc2, sh2,
                                                      nullptr, nullptr);
    // tokens = maxpool_k(f3 @ w4^T + b4), f4 never materialized
    gemm_bt<4><<<dim3(3, rows/128), 256, 0, stream>>>(f3, w4b, nullptr, nullptr, 384, 512,
                                                      b4, nullptr, nullptr,
                                                      nullptr, tokens + (size_t)g0*384);
  }
}

// Round 11
// 1349.268 us; speedup vs baseline: 1.3091x; 1.0056x over previous
//
#include <hip/hip_runtime.h>
#include <stdint.h>

// ---------------- problem constants ----------------
#define PB 16            // batches
#define PN 8192          // points per batch
#define PG 512           // FPS samples (centers) per batch
#define PK 32            // knn group size
#define PTOK 384
#define PM (PB*PG)       // 8192 groups total
#define PMK (PM*PK)      // 262144 MLP rows
static constexpr float BN_EPS_C = 1e-5f;

typedef short bh8  __attribute__((ext_vector_type(8)));
typedef float f32x4 __attribute__((ext_vector_type(4)));

__device__ __forceinline__ short f2bf(float f){
  unsigned u = __float_as_uint(f);
  unsigned r = u + 0x7fffu + ((u>>16)&1u);   // RNE
  return (short)(r>>16);
}
__device__ __forceinline__ float bf2f(short s){
  return __uint_as_float(((unsigned)(unsigned short)s)<<16);
}
__device__ __forceinline__ void gload16(const void* g, void* l){
  __builtin_amdgcn_global_load_lds((const __attribute__((address_space(1))) unsigned int*)g,
                                   (__attribute__((address_space(3))) unsigned int*)l,
                                   16, 0, 0);
}

// ---------------- 1. FPS: spatially-pruned, EXACT (R10 + finer cells + f4 bcast)
// Exactness as R10: wave skips its md-update iff dmin2(waveBBox,c)*0.999999 >=
// wave md-max — a provable no-op; md values stay bit-identical. Key =
// (bits(md)<<32)|(8191-origj): u64 max == numpy first-index argmax under any
// storage permutation (per-point key max retained — (bv,bi) tracking would
// break orig-index ties in sorted order). New vs R10: 8x8x8 Morton cells
// (tighter wave bboxes => higher skip rate; rate-only, never values) and
// float4 coord mirror Lc => winner broadcast is ONE ds_read_b128.
__global__ __launch_bounds__(1024, 4) void fps_kernel(const float* __restrict__ points,
                                                      float* __restrict__ centers){
#pragma clang fp contract(off)
  const int b = blockIdx.x;
  const int t = threadIdx.x;
  const float* P = points + (size_t)b*PN*3;
  __shared__ float4 Lc[PN];                        // 128 KB coords by ORIG index
  __shared__ unsigned short sidx[PN];              // 16 KB sorted->orig
  __shared__ int shist[512];                       // 9-bit Morton bins
  __shared__ int spart[64];
  __shared__ unsigned long long swa[3];
  if (t < 512) shist[t] = 0;
  if (t < 3)   swa[t] = 0ull;
  __syncthreads();
  // pass 1: load, mirror to Lc, histogram 9-bit Morton cell ([-4,4]^3, 8x8x8)
  int mycell[8];
#pragma unroll
  for (int i=0;i<8;i++){
    int j = i*1024 + t;
    float x=P[j*3+0], y=P[j*3+1], z=P[j*3+2];
    Lc[j] = make_float4(x,y,z,0.f);
    int qx=(int)fminf(fmaxf((x+4.f)*1.0f,0.f),7.f);
    int qy=(int)fminf(fmaxf((y+4.f)*1.0f,0.f),7.f);
    int qz=(int)fminf(fmaxf((z+4.f)*1.0f,0.f),7.f);
    int mc = (qx&1)|((qx&2)<<2)|((qx&4)<<4)
           | ((qy&1)<<1)|((qy&2)<<3)|((qy&4)<<5)
           | ((qz&1)<<2)|((qz&2)<<4)|((qz&4)<<6);
    mycell[i]=mc;
    atomicAdd(&shist[mc],1);
  }
  __syncthreads();
  // exclusive prefix over 512 bins: 64 locals -> serial 64 -> add back
  if (t < 64){
    int acc=0;
#pragma unroll
    for (int k=0;k<8;k++){ int h=shist[t*8+k]; shist[t*8+k]=acc; acc+=h; }
    spart[t]=acc;
  }
  __syncthreads();
  if (t==0){ int acc=0; for (int k=0;k<64;k++){ int h=spart[k]; spart[k]=acc; acc+=h; } }
  __syncthreads();
  if (t < 64){
    int off=spart[t];
#pragma unroll
    for (int k=0;k<8;k++) shist[t*8+k] += off;
  }
  __syncthreads();
  // pass 2: scatter ranks (in-cell order nondeterministic — values unaffected)
#pragma unroll
  for (int i=0;i<8;i++){
    int j = i*1024 + t;
    int r = atomicAdd(&shist[mycell[i]],1);
    sidx[r] = (unsigned short)j;
  }
  __syncthreads();
  // pass 3: gather sorted ownership (thread t: sorted slots [8t,8t+8)) + wave bbox
  float px[8],py[8],pz[8],md[8]; int lowc[8];
  float tlx=1e30f,tly=1e30f,tlz=1e30f,thx=-1e30f,thy=-1e30f,thz=-1e30f;
#pragma unroll
  for (int i=0;i<8;i++){
    int oj = sidx[t*8+i];
    float4 p4 = Lc[oj];                            // scattered b128 gather (one-time)
    float x=p4.x, y=p4.y, z=p4.z;
    px[i]=x; py[i]=y; pz[i]=z; md[i]=1e10f; lowc[i]=PN-1-oj;
    tlx=fminf(tlx,x); thx=fmaxf(thx,x);
    tly=fminf(tly,y); thy=fmaxf(thy,y);
    tlz=fminf(tlz,z); thz=fmaxf(thz,z);
  }
#pragma unroll
  for (int off=32; off; off>>=1){
    tlx=fminf(tlx,__shfl_xor(tlx,off)); thx=fmaxf(thx,__shfl_xor(thx,off));
    tly=fminf(tly,__shfl_xor(tly,off)); thy=fmaxf(thy,__shfl_xor(thy,off));
    tlz=fminf(tlz,__shfl_xor(tlz,off)); thz=fmaxf(thz,__shfl_xor(thz,off));
  }
  unsigned long long wkey = ((unsigned long long)0x7F800000u)<<32;  // +inf: no skip pre-store
  float cx=P[0], cy=P[1], cz=P[2];                 // start = orig point 0
  if (t==0){ float* c = centers + (size_t)b*PG*3; c[0]=cx; c[1]=cy; c[2]=cz; }
  const int lane = t & 63;
  __syncthreads();
  for (int g=1; g<PG; g++){
    const int sl = g%3, ns = (g+1)%3;
    float ddx=fmaxf(fmaxf(tlx-cx, cx-thx),0.f);    // wave-uniform skip test
    float ddy=fmaxf(fmaxf(tly-cy, cy-thy),0.f);
    float ddz=fmaxf(fmaxf(tlz-cz, cz-thz),0.f);
    float dmin2=((ddx*ddx+ddy*ddy)+ddz*ddz)*0.999999f;   // conservative bound
    if (!(dmin2 >= __uint_as_float((unsigned)(wkey>>32)))){
      unsigned long long bk = 0ull;
#pragma unroll
      for (int i=0;i<8;i++){
        float dx=px[i]-cx, dy=py[i]-cy, dz=pz[i]-cz;
        float d2 = (dx*dx + dy*dy) + dz*dz;        // numpy order, no fma
        md[i] = fminf(md[i], d2);
        unsigned long long ki = ((unsigned long long)__float_as_uint(md[i])<<32)
                              | (unsigned)lowc[i];
        if (ki > bk) bk = ki;
      }
#pragma unroll
      for (int mask=32; mask; mask>>=1){
        unsigned long long o = __shfl_xor(bk, mask);
        if (o > bk) bk = o;
      }
      wkey = bk;                                   // wave max, all lanes
    }
    if (lane==0) atomicMax(&swa[sl], wkey);
    if (t==0) swa[ns] = 0ull;                      // reset future slot (barrier-separated)
    __syncthreads();                               // the only barrier per round
    unsigned long long w = swa[sl];
    int j = PN-1 - (int)(w & 0xFFFFFFFFu);
    float4 c4 = Lc[j];                             // ONE broadcast ds_read_b128
    cx = c4.x; cy = c4.y; cz = c4.z;
    if (t==0){ float* cc = centers + ((size_t)b*PG + g)*3; cc[0]=cx; cc[1]=cy; cc[2]=cz; }
  }
}

// ---------------- 2. KNN: exact top-32, incremental lmin + owner rescan --------
__global__ __launch_bounds__(256) void knn_kernel(const float* __restrict__ points,
                                                  const float* __restrict__ centers,
                                                  float* __restrict__ groups){
#pragma clang fp contract(off)
  const int m = blockIdx.x;
  const int b = m >> 9;       // m / PG
  const int t = threadIdx.x;
  const float* P = points + (size_t)b*PN*3;
  const float* c = centers + (size_t)m*3;
  const float cx=c[0], cy=c[1], cz=c[2];
  const float cn = (cx*cx + cy*cy) + cz*cz;
  unsigned long long key[PK];
#pragma unroll
  for (int i=0;i<PK;i++){
    int j = i*256 + t;
    float x=P[j*3+0], y=P[j*3+1], z=P[j*3+2];
    float pn = (x*x + y*y) + z*z;
    float e  = (cx*x + cy*y) + cz*z;
    float d2 = (cn + pn) - 2.0f*e;                 // reference formula
    unsigned u = __float_as_uint(d2);
    u ^= (u & 0x80000000u) ? 0xFFFFFFFFu : 0x80000000u;   // total order
    key[i] = ((unsigned long long)u << 32) | (unsigned)j;
  }
  unsigned long long lmin = key[0];
#pragma unroll
  for (int i=1;i<PK;i++) if (key[i] < lmin) lmin = key[i];
  __shared__ unsigned long long swk[2][4];
  __shared__ int s_idx[PK];
  const int lane = t & 63, wid = t >> 6;
  for (int it=0; it<PK; it++){
    unsigned long long v = lmin;
#pragma unroll
    for (int off=32; off; off>>=1){
      unsigned long long o = __shfl_down(v, off);
      if (o < v) v = o;
    }
    if (lane==0) swk[it&1][wid] = v;
    __syncthreads();                               // the only barrier per round
    unsigned long long w = swk[it&1][0];
#pragma unroll
    for (int q=1;q<4;q++) if (swk[it&1][q] < w) w = swk[it&1][q];
    int wj = (int)(w & 0xFFFFFFFFull);
    if (t==0) s_idx[it] = wj;
    if ((wj & 255) == t){                          // owner-only knockout + rescan
#pragma unroll
      for (int i=0;i<PK;i++) if (key[i] == w) key[i] = ~0ull;
      lmin = key[0];
#pragma unroll
      for (int i=1;i<PK;i++) if (key[i] < lmin) lmin = key[i];
    }
  }
  __syncthreads();
  if (t < PK*3){
    int k = t/3, cc = t - k*3;
    int j = s_idx[k];
    groups[((size_t)m*PK + k)*3 + cc] = P[j*3+cc] - c[cc];
  }
}

// ---------------- 3. layer1: 3->128 linear + BN1 + ReLU, fp32 VALU ----------------
__global__ __launch_bounds__(256) void layer1_kernel(const float* __restrict__ groups,
                                                     const float* __restrict__ w1,
                                                     const float* __restrict__ sc1,
                                                     const float* __restrict__ sh1,
                                                     short* __restrict__ f1){
  int idx = blockIdx.x*256 + threadIdx.x;   // [mk, d], d fastest (slice-local)
  int d  = idx & 127;
  int mk = idx >> 7;
  const float* x = groups + (size_t)mk*3;
  float a = x[0]*w1[d*3+0] + x[1]*w1[d*3+1] + x[2]*w1[d*3+2];
  float y = a*sc1[d] + sh1[d];
  f1[idx] = f2bf(fmaxf(y, 0.f));
}

// ---------------- 4. bf16 MFMA GEMM: C[M,N] = A[M,K] @ B[N,K]^T ----------------
// grid = (bn, bm): bn fastest => blocks sharing an A-tile are dispatch-adjacent.
// EPI 0: store fp32 raw (H).
// EPI 1: +bias[col], store bf16.
// EPI 2: relu(bn2(acc+H[row/32])), store bf16.
// EPI 3: +bias, store bf16 AND fused k-maxpool -> pool_bf (128 rows = 4 groups).
// EPI 4: +bias, fused k-maxpool only -> pool_f (f4 never materialized).
template<int EPI>
__global__ __launch_bounds__(256) void gemm_bt(const short* __restrict__ A,
                                               const short* __restrict__ Bw,
                                               float* __restrict__ Cf,
                                               short* __restrict__ Cb,
                                               int Nn, int Kd,
                                               const float* __restrict__ aux0,
                                               const float* __restrict__ scale,
                                               const float* __restrict__ shift,
                                               short* __restrict__ pool_bf,
                                               float* __restrict__ pool_f){
  __shared__ __align__(16) short smem[(EPI>=3) ? 16384 : 8192];   // 32 KB / 16 KB
  short* As = smem;
  short* Bs = smem + 4096;
  const int bm = blockIdx.y, bn = blockIdx.x;      // bn fastest (A-tile adjacency)
  const int t = threadIdx.x;
  const int lane = t & 63, wid = t >> 6;
  const int wr = wid >> 1, wc = wid & 1;          // 2x2 waves, each 64x64
  f32x4 acc[4][4] = {};
  const int srow = lane >> 2;                      // staging: row within 16-row chunk
  const int scol = (lane & 3) * 8;                 // staging: 8-elem column offset
  const int frow = lane & 15;                      // fragment row/col
  const int fk   = (lane >> 4) * 8;                // fragment k offset
  for (int k0 = 0; k0 < Kd; k0 += 32){
    const size_t abase = ((size_t)bm*128) * Kd + k0 + scol;
    const size_t bbase = ((size_t)bn*128) * Kd + k0 + scol;
    for (int q=0;q<2;q++){
      int chunk = wid*2 + q;                       // 8 chunks x 16 rows = 128 rows
      gload16(A  + abase + (size_t)(chunk*16 + srow)*Kd, &As[chunk*512]);
      gload16(Bw + bbase + (size_t)(chunk*16 + srow)*Kd, &Bs[chunk*512]);
    }
    __syncthreads();                               // vmcnt(0) drained by compiler
    bh8 af[4], bf[4];
    for (int i=0;i<4;i++) af[i] = *(const bh8*)&As[(wr*64 + i*16 + frow)*32 + fk];
    for (int j=0;j<4;j++) bf[j] = *(const bh8*)&Bs[(wc*64 + j*16 + frow)*32 + fk];
    for (int i=0;i<4;i++)
      for (int j=0;j<4;j++)
        acc[i][j] = __builtin_amdgcn_mfma_f32_16x16x32_bf16(af[i], bf[j], acc[i][j], 0, 0, 0);
    __syncthreads();                               // protect LDS for next stage
  }
  const int rb = (lane >> 4) * 4;                  // C/D: col=lane&15, row=(lane>>4)*4+reg
  const int cb = lane & 15;
  for (int i=0;i<4;i++){
    for (int j=0;j<4;j++){
      int lcol = wc*64 + j*16 + cb;
      int col  = bn*128 + lcol;
      for (int r=0;r<4;r++){
        int lrow = wr*64 + i*16 + rb + r;
        size_t row = (size_t)bm*128 + lrow;
        float v = acc[i][j][r];
        if (EPI == 0){
          Cf[row*Nn + col] = v;
        } else if (EPI == 1){
          Cb[row*Nn + col] = f2bf(v + aux0[col]);
        } else if (EPI == 2){
          v += aux0[(row >> 5)*Nn + col];          // + g@w3a^T per group (slice-local)
          v = v*scale[col] + shift[col];           // BN2
          Cb[row*Nn + col] = f2bf(fmaxf(v, 0.f));  // ReLU
        } else {
          short bv = f2bf(v + aux0[col]);
          if (EPI == 3) Cb[row*Nn + col] = bv;     // f2 still needed downstream
          smem[lrow*128 + lcol] = bv;              // stage tile for fused pool
        }
      }
    }
  }
  if (EPI >= 3){
    __syncthreads();                               // tile complete in LDS
    int c = t & 127, gsel = t >> 7;                // 256 thr -> 2 (group,col) each
#pragma unroll
    for (int gg=0; gg<2; gg++){
      int g = gsel*2 + gg;                         // 0..3 within tile
      float mx = -3.4e38f;
#pragma unroll
      for (int k=0;k<PK;k++) mx = fmaxf(mx, bf2f(smem[(g*32 + k)*128 + c]));
      size_t grow = (size_t)bm*4 + g;
      int gcol = bn*128 + c;
      if (EPI == 3) pool_bf[grow*256  + gcol] = f2bf(mx);
      else          pool_f [grow*PTOK + gcol] = mx;
    }
  }
}

// ---------------- 0. weight conversion + BN folding ----------------
__global__ __launch_bounds__(256) void prep_kernel(const float* __restrict__ w2,
    const float* __restrict__ w3, const float* __restrict__ w4,
    const float* __restrict__ g1, const float* __restrict__ be1,
    const float* __restrict__ mu1, const float* __restrict__ va1,
    const float* __restrict__ g2, const float* __restrict__ be2,
    const float* __restrict__ mu2, const float* __restrict__ va2,
    short* __restrict__ w2b, short* __restrict__ w3ab, short* __restrict__ w3bb,
    short* __restrict__ w4b, float* __restrict__ sc1, float* __restrict__ sh1,
    float* __restrict__ sc2, float* __restrict__ sh2){
  int i = blockIdx.x*256 + threadIdx.x;
  if (i < 256*128) w2b[i] = f2bf(w2[i]);
  if (i < 512*512){
    int f = i >> 9, e = i & 511;
    short v = f2bf(w3[i]);
    if (e < 256) w3ab[f*256 + e] = v; else w3bb[f*256 + (e-256)] = v;
  }
  if (i < 384*512) w4b[i] = f2bf(w4[i]);
  if (i < 128){ float s = g1[i]*rsqrtf(va1[i] + BN_EPS_C); sc1[i]=s; sh1[i]=be1[i]-mu1[i]*s; }
  if (i < 512){ float s = g2[i]*rsqrtf(va2[i] + BN_EPS_C); sc2[i]=s; sh2[i]=be2[i]-mu2[i]*s; }
}

// ---------------- launcher ----------------
extern "C" void kernel_launch(void* const* d_in, const int* in_sizes, int n_in,
                              void* d_out, int out_size, void* d_ws, size_t ws_size,
                              hipStream_t stream){
  const float* points = (const float*)d_in[0];
  const float* w1  = (const float*)d_in[1];
  const float* g1  = (const float*)d_in[2];
  const float* be1 = (const float*)d_in[3];
  const float* mu1 = (const float*)d_in[4];
  const float* va1 = (const float*)d_in[5];
  const float* w2  = (const float*)d_in[6];
  const float* b2  = (const float*)d_in[7];
  const float* w3  = (const float*)d_in[8];
  const float* g2  = (const float*)d_in[9];
  const float* be2 = (const float*)d_in[10];
  const float* mu2 = (const float*)d_in[11];
  const float* va2 = (const float*)d_in[12];
  const float* w4  = (const float*)d_in[13];
  const float* b4  = (const float*)d_in[14];
  float* tokens  = (float*)d_out;                       // [PM, 384]
  float* centers = (float*)d_out + (size_t)PM*PTOK;     // [PM, 3]

  // ---- fixed workspace region (~25.1 MB) ----
  char* ws = (char*)d_ws;
  float* grp  = (float*)(ws + 0);              // 262144x3 fp32  = 3 MB
  short* gbuf = (short*)(ws + 3145728ull);     // 8192x256 bf16  = 4 MB
  float* Hbuf = (float*)(ws + 7340032ull);     // 8192x512 fp32  = 16 MB
  short* w2b  = (short*)(ws + 24117248ull);    // 256x128 bf16
  short* w3ab = (short*)(ws + 24182784ull);    // 512x256 bf16
  short* w3bb = (short*)(ws + 24444928ull);    // 512x256 bf16
  short* w4b  = (short*)(ws + 24707072ull);    // 384x512 bf16
  float* sc1  = (float*)(ws + 25100288ull);
  float* sh1  = (float*)(ws + 25100800ull);
  float* sc2  = (float*)(ws + 25101312ull);
  float* sh2  = (float*)(ws + 25103360ull);
  const size_t sliceBase = 25105408ull;

  // ---- adaptive row-slicing: peak slice use = 1792 bytes/row ----
  size_t avail = (ws_size > sliceBase) ? (ws_size - sliceBase) : 0;
  long long smax = (long long)(avail / 1792u);
  int S = (int)((smax / 4096) * 4096);
  if (S > PMK) S = PMK;
  if (S < 4096) S = 4096;   // below ~32 MB ws nothing fits; best effort
  char* sl = ws + sliceBase;

  prep_kernel<<<1024, 256, 0, stream>>>(w2, w3, w4, g1, be1, mu1, va1, g2, be2, mu2, va2,
                                        w2b, w3ab, w3bb, w4b, sc1, sh1, sc2, sh2);
  fps_kernel<<<PB, 1024, 0, stream>>>(points, centers);
  knn_kernel<<<PM, 256, 0, stream>>>(points, centers, grp);

  for (int r0 = 0; r0 < PMK; r0 += S){
    int rows = (PMK - r0 < S) ? (PMK - r0) : S;    // multiple of 4096
    int g0 = r0 >> 5, ng = rows >> 5;              // groups in slice
    short* f1 = (short*)(sl + 0);                  // rows x 128 bf16
    short* f2 = (short*)(sl + (size_t)S*256);      // rows x 256 bf16
    short* f3 = (short*)(sl + (size_t)S*768);      // rows x 512 bf16

    layer1_kernel<<<(rows*128)/256, 256, 0, stream>>>(grp + (size_t)r0*3, w1, sc1, sh1, f1);
    // f2 = f1 @ w2^T + b2, fused g = maxpool_k(f2)
    gemm_bt<3><<<dim3(2, rows/128), 256, 0, stream>>>(f1, w2b, nullptr, f2, 256, 128,
                                                      b2, nullptr, nullptr,
                                                      gbuf + (size_t)g0*256, nullptr);
    // H = g @ w3[:, :256]^T   (per-group part of the concat GEMM)
    gemm_bt<0><<<dim3(4, ng/128), 256, 0, stream>>>(gbuf + (size_t)g0*256, w3ab,
                                                    Hbuf + (size_t)g0*512, nullptr, 512, 256,
                                                    nullptr, nullptr, nullptr, nullptr, nullptr);
    // f3 = relu(bn2(f2 @ w3[:, 256:]^T + H[group]))
    gemm_bt<2><<<dim3(4, rows/128), 256, 0, stream>>>(f2, w3bb, nullptr, f3, 512, 256,
                                                      Hbuf + (size_t)g0*512, sc2, sh2,
                                                      nullptr, nullptr);
    // tokens = maxpool_k(f3 @ w4^T + b4), f4 never materialized
    gemm_bt<4><<<dim3(3, rows/128), 256, 0, stream>>>(f3, w4b, nullptr, nullptr, 384, 512,
                                                      b4, nullptr, nullptr,
                                                      nullptr, tokens + (size_t)g0*384);
  }
}

// Round 12
// 1316.767 us; speedup vs baseline: 1.3414x; 1.0247x over previous
//
#include <hip/hip_runtime.h>
#include <stdint.h>

// ---------------- problem constants ----------------
#define PB 16            // batches
#define PN 8192          // points per batch
#define PG 512           // FPS samples (centers) per batch
#define PK 32            // knn group size
#define PTOK 384
#define PM (PB*PG)       // 8192 groups total
#define PMK (PM*PK)      // 262144 MLP rows
static constexpr float BN_EPS_C = 1e-5f;

typedef short bh8  __attribute__((ext_vector_type(8)));
typedef float f32x4 __attribute__((ext_vector_type(4)));

__device__ __forceinline__ short f2bf(float f){
  unsigned u = __float_as_uint(f);
  unsigned r = u + 0x7fffu + ((u>>16)&1u);   // RNE
  return (short)(r>>16);
}
__device__ __forceinline__ float bf2f(short s){
  return __uint_as_float(((unsigned)(unsigned short)s)<<16);
}
__device__ __forceinline__ void gload16(const void* g, void* l){
  __builtin_amdgcn_global_load_lds((const __attribute__((address_space(1))) unsigned int*)g,
                                   (__attribute__((address_space(3))) unsigned int*)l,
                                   16, 0, 0);
}

// ---------------- 1. FPS: spatially-pruned, EXACT (R11, at structural floor) ---
__global__ __launch_bounds__(1024, 4) void fps_kernel(const float* __restrict__ points,
                                                      float* __restrict__ centers){
#pragma clang fp contract(off)
  const int b = blockIdx.x;
  const int t = threadIdx.x;
  const float* P = points + (size_t)b*PN*3;
  __shared__ float4 Lc[PN];                        // 128 KB coords by ORIG index
  __shared__ unsigned short sidx[PN];              // 16 KB sorted->orig
  __shared__ int shist[512];                       // 9-bit Morton bins
  __shared__ int spart[64];
  __shared__ unsigned long long swa[3];
  if (t < 512) shist[t] = 0;
  if (t < 3)   swa[t] = 0ull;
  __syncthreads();
  int mycell[8];
#pragma unroll
  for (int i=0;i<8;i++){
    int j = i*1024 + t;
    float x=P[j*3+0], y=P[j*3+1], z=P[j*3+2];
    Lc[j] = make_float4(x,y,z,0.f);
    int qx=(int)fminf(fmaxf((x+4.f)*1.0f,0.f),7.f);
    int qy=(int)fminf(fmaxf((y+4.f)*1.0f,0.f),7.f);
    int qz=(int)fminf(fmaxf((z+4.f)*1.0f,0.f),7.f);
    int mc = (qx&1)|((qx&2)<<2)|((qx&4)<<4)
           | ((qy&1)<<1)|((qy&2)<<3)|((qy&4)<<5)
           | ((qz&1)<<2)|((qz&2)<<4)|((qz&4)<<6);
    mycell[i]=mc;
    atomicAdd(&shist[mc],1);
  }
  __syncthreads();
  if (t < 64){
    int acc=0;
#pragma unroll
    for (int k=0;k<8;k++){ int h=shist[t*8+k]; shist[t*8+k]=acc; acc+=h; }
    spart[t]=acc;
  }
  __syncthreads();
  if (t==0){ int acc=0; for (int k=0;k<64;k++){ int h=spart[k]; spart[k]=acc; acc+=h; } }
  __syncthreads();
  if (t < 64){
    int off=spart[t];
#pragma unroll
    for (int k=0;k<8;k++) shist[t*8+k] += off;
  }
  __syncthreads();
#pragma unroll
  for (int i=0;i<8;i++){
    int j = i*1024 + t;
    int r = atomicAdd(&shist[mycell[i]],1);
    sidx[r] = (unsigned short)j;
  }
  __syncthreads();
  float px[8],py[8],pz[8],md[8]; int lowc[8];
  float tlx=1e30f,tly=1e30f,tlz=1e30f,thx=-1e30f,thy=-1e30f,thz=-1e30f;
#pragma unroll
  for (int i=0;i<8;i++){
    int oj = sidx[t*8+i];
    float4 p4 = Lc[oj];
    float x=p4.x, y=p4.y, z=p4.z;
    px[i]=x; py[i]=y; pz[i]=z; md[i]=1e10f; lowc[i]=PN-1-oj;
    tlx=fminf(tlx,x); thx=fmaxf(thx,x);
    tly=fminf(tly,y); thy=fmaxf(thy,y);
    tlz=fminf(tlz,z); thz=fmaxf(thz,z);
  }
#pragma unroll
  for (int off=32; off; off>>=1){
    tlx=fminf(tlx,__shfl_xor(tlx,off)); thx=fmaxf(thx,__shfl_xor(thx,off));
    tly=fminf(tly,__shfl_xor(tly,off)); thy=fmaxf(thy,__shfl_xor(thy,off));
    tlz=fminf(tlz,__shfl_xor(tlz,off)); thz=fmaxf(thz,__shfl_xor(thz,off));
  }
  unsigned long long wkey = ((unsigned long long)0x7F800000u)<<32;
  float cx=P[0], cy=P[1], cz=P[2];
  if (t==0){ float* c = centers + (size_t)b*PG*3; c[0]=cx; c[1]=cy; c[2]=cz; }
  const int lane = t & 63;
  __syncthreads();
  for (int g=1; g<PG; g++){
    const int sl = g%3, ns = (g+1)%3;
    float ddx=fmaxf(fmaxf(tlx-cx, cx-thx),0.f);
    float ddy=fmaxf(fmaxf(tly-cy, cy-thy),0.f);
    float ddz=fmaxf(fmaxf(tlz-cz, cz-thz),0.f);
    float dmin2=((ddx*ddx+ddy*ddy)+ddz*ddz)*0.999999f;
    if (!(dmin2 >= __uint_as_float((unsigned)(wkey>>32)))){
      unsigned long long bk = 0ull;
#pragma unroll
      for (int i=0;i<8;i++){
        float dx=px[i]-cx, dy=py[i]-cy, dz=pz[i]-cz;
        float d2 = (dx*dx + dy*dy) + dz*dz;
        md[i] = fminf(md[i], d2);
        unsigned long long ki = ((unsigned long long)__float_as_uint(md[i])<<32)
                              | (unsigned)lowc[i];
        if (ki > bk) bk = ki;
      }
#pragma unroll
      for (int mask=32; mask; mask>>=1){
        unsigned long long o = __shfl_xor(bk, mask);
        if (o > bk) bk = o;
      }
      wkey = bk;
    }
    if (lane==0) atomicMax(&swa[sl], wkey);
    if (t==0) swa[ns] = 0ull;
    __syncthreads();
    unsigned long long w = swa[sl];
    int j = PN-1 - (int)(w & 0xFFFFFFFFu);
    float4 c4 = Lc[j];
    cx = c4.x; cy = c4.y; cz = c4.z;
    if (t==0){ float* cc = centers + ((size_t)b*PG + g)*3; cc[0]=cx; cc[1]=cy; cc[2]=cz; }
  }
}

// ---------------- 2. KNN: exact top-32, incremental lmin + owner rescan --------
__global__ __launch_bounds__(256) void knn_kernel(const float* __restrict__ points,
                                                  const float* __restrict__ centers,
                                                  float* __restrict__ groups){
#pragma clang fp contract(off)
  const int m = blockIdx.x;
  const int b = m >> 9;       // m / PG
  const int t = threadIdx.x;
  const float* P = points + (size_t)b*PN*3;
  const float* c = centers + (size_t)m*3;
  const float cx=c[0], cy=c[1], cz=c[2];
  const float cn = (cx*cx + cy*cy) + cz*cz;
  unsigned long long key[PK];
#pragma unroll
  for (int i=0;i<PK;i++){
    int j = i*256 + t;
    float x=P[j*3+0], y=P[j*3+1], z=P[j*3+2];
    float pn = (x*x + y*y) + z*z;
    float e  = (cx*x + cy*y) + cz*z;
    float d2 = (cn + pn) - 2.0f*e;                 // reference formula
    unsigned u = __float_as_uint(d2);
    u ^= (u & 0x80000000u) ? 0xFFFFFFFFu : 0x80000000u;   // total order
    key[i] = ((unsigned long long)u << 32) | (unsigned)j;
  }
  unsigned long long lmin = key[0];
#pragma unroll
  for (int i=1;i<PK;i++) if (key[i] < lmin) lmin = key[i];
  __shared__ unsigned long long swk[2][4];
  __shared__ int s_idx[PK];
  const int lane = t & 63, wid = t >> 6;
  for (int it=0; it<PK; it++){
    unsigned long long v = lmin;
#pragma unroll
    for (int off=32; off; off>>=1){
      unsigned long long o = __shfl_down(v, off);
      if (o < v) v = o;
    }
    if (lane==0) swk[it&1][wid] = v;
    __syncthreads();                               // the only barrier per round
    unsigned long long w = swk[it&1][0];
#pragma unroll
    for (int q=1;q<4;q++) if (swk[it&1][q] < w) w = swk[it&1][q];
    int wj = (int)(w & 0xFFFFFFFFull);
    if (t==0) s_idx[it] = wj;
    if ((wj & 255) == t){                          // owner-only knockout + rescan
#pragma unroll
      for (int i=0;i<PK;i++) if (key[i] == w) key[i] = ~0ull;
      lmin = key[0];
#pragma unroll
      for (int i=1;i<PK;i++) if (key[i] < lmin) lmin = key[i];
    }
  }
  __syncthreads();
  if (t < PK*3){
    int k = t/3, cc = t - k*3;
    int j = s_idx[k];
    groups[((size_t)m*PK + k)*3 + cc] = P[j*3+cc] - c[cc];
  }
}

// ---------------- 3. layer1: 3->128 linear + BN1 + ReLU, fp32 VALU ----------------
__global__ __launch_bounds__(256) void layer1_kernel(const float* __restrict__ groups,
                                                     const float* __restrict__ w1,
                                                     const float* __restrict__ sc1,
                                                     const float* __restrict__ sh1,
                                                     short* __restrict__ f1){
  int idx = blockIdx.x*256 + threadIdx.x;   // [mk, d], d fastest (slice-local)
  int d  = idx & 127;
  int mk = idx >> 7;
  const float* x = groups + (size_t)mk*3;
  float a = x[0]*w1[d*3+0] + x[1]*w1[d*3+1] + x[2]*w1[d*3+2];
  float y = a*sc1[d] + sh1[d];
  f1[idx] = f2bf(fmaxf(y, 0.f));
}

// ---------------- 4. bf16 MFMA GEMM: C[M,N] = A[M,K] @ B[N,K]^T ----------------
// 1D grid, XCD-aware decomposition: all bn sharing a bm get ids congruent mod 8
// => same XCD (round-robin assignment) => A-tile fetched once into that XCD's
// L2 and re-read from L2 for the other bn (HBM A-traffic / NB). Bijection:
// id = a*8*NB + b*8 + c -> bm = 8a+c, bn = b (requires MB%8==0; runtime
// fallback to plain decompose otherwise — only the tiny H-GEMM can hit it).
// EPI 0: store fp32 raw (H).      EPI 1: +bias[col], store bf16.
// EPI 2: relu(bn2(acc+H[row/32])), store bf16.
// EPI 3: +bias, store bf16 AND fused k-maxpool -> pool_bf (128 rows = 4 groups).
// EPI 4: +bias, fused k-maxpool only -> pool_f (f4 never materialized).
template<int EPI>
__global__ __launch_bounds__(256) void gemm_bt(const short* __restrict__ A,
                                               const short* __restrict__ Bw,
                                               float* __restrict__ Cf,
                                               short* __restrict__ Cb,
                                               int Nn, int Kd,
                                               const float* __restrict__ aux0,
                                               const float* __restrict__ scale,
                                               const float* __restrict__ shift,
                                               short* __restrict__ pool_bf,
                                               float* __restrict__ pool_f){
  __shared__ __align__(16) short smem[(EPI>=3) ? 16384 : 8192];   // 32 KB / 16 KB
  short* As = smem;
  short* Bs = smem + 4096;
  const int NB = Nn >> 7;
  const int MB = (int)gridDim.x / NB;
  int bm, bn;
  {
    int id = blockIdx.x;
    if ((MB & 7) == 0){
      int c = id & 7, q = id >> 3;
      bn = q % NB;
      bm = (q / NB)*8 + c;
    } else {
      bn = id % NB;
      bm = id / NB;
    }
  }
  const int t = threadIdx.x;
  const int lane = t & 63, wid = t >> 6;
  const int wr = wid >> 1, wc = wid & 1;          // 2x2 waves, each 64x64
  f32x4 acc[4][4] = {};
  const int srow = lane >> 2;                      // staging: row within 16-row chunk
  const int scol = (lane & 3) * 8;                 // staging: 8-elem column offset
  const int frow = lane & 15;                      // fragment row/col
  const int fk   = (lane >> 4) * 8;                // fragment k offset
  for (int k0 = 0; k0 < Kd; k0 += 32){
    const size_t abase = ((size_t)bm*128) * Kd + k0 + scol;
    const size_t bbase = ((size_t)bn*128) * Kd + k0 + scol;
    for (int q=0;q<2;q++){
      int chunk = wid*2 + q;                       // 8 chunks x 16 rows = 128 rows
      gload16(A  + abase + (size_t)(chunk*16 + srow)*Kd, &As[chunk*512]);
      gload16(Bw + bbase + (size_t)(chunk*16 + srow)*Kd, &Bs[chunk*512]);
    }
    __syncthreads();                               // vmcnt(0) drained by compiler
    bh8 af[4], bf[4];
    for (int i=0;i<4;i++) af[i] = *(const bh8*)&As[(wr*64 + i*16 + frow)*32 + fk];
    for (int j=0;j<4;j++) bf[j] = *(const bh8*)&Bs[(wc*64 + j*16 + frow)*32 + fk];
    for (int i=0;i<4;i++)
      for (int j=0;j<4;j++)
        acc[i][j] = __builtin_amdgcn_mfma_f32_16x16x32_bf16(af[i], bf[j], acc[i][j], 0, 0, 0);
    __syncthreads();                               // protect LDS for next stage
  }
  const int rb = (lane >> 4) * 4;                  // C/D: col=lane&15, row=(lane>>4)*4+reg
  const int cb = lane & 15;
  for (int i=0;i<4;i++){
    for (int j=0;j<4;j++){
      int lcol = wc*64 + j*16 + cb;
      int col  = bn*128 + lcol;
      for (int r=0;r<4;r++){
        int lrow = wr*64 + i*16 + rb + r;
        size_t row = (size_t)bm*128 + lrow;
        float v = acc[i][j][r];
        if (EPI == 0){
          Cf[row*Nn + col] = v;
        } else if (EPI == 1){
          Cb[row*Nn + col] = f2bf(v + aux0[col]);
        } else if (EPI == 2){
          v += aux0[(row >> 5)*Nn + col];          // + g@w3a^T per group (slice-local)
          v = v*scale[col] + shift[col];           // BN2
          Cb[row*Nn + col] = f2bf(fmaxf(v, 0.f));  // ReLU
        } else {
          short bv = f2bf(v + aux0[col]);
          if (EPI == 3) Cb[row*Nn + col] = bv;     // f2 still needed downstream
          smem[lrow*128 + lcol] = bv;              // stage tile for fused pool
        }
      }
    }
  }
  if (EPI >= 3){
    __syncthreads();                               // tile complete in LDS
    int c = t & 127, gsel = t >> 7;                // 256 thr -> 2 (group,col) each
#pragma unroll
    for (int gg=0; gg<2; gg++){
      int g = gsel*2 + gg;                         // 0..3 within tile
      float mx = -3.4e38f;
#pragma unroll
      for (int k=0;k<PK;k++) mx = fmaxf(mx, bf2f(smem[(g*32 + k)*128 + c]));
      size_t grow = (size_t)bm*4 + g;
      int gcol = bn*128 + c;
      if (EPI == 3) pool_bf[grow*256  + gcol] = f2bf(mx);
      else          pool_f [grow*PTOK + gcol] = mx;
    }
  }
}

// ---------------- 0. weight conversion + BN folding ----------------
__global__ __launch_bounds__(256) void prep_kernel(const float* __restrict__ w2,
    const float* __restrict__ w3, const float* __restrict__ w4,
    const float* __restrict__ g1, const float* __restrict__ be1,
    const float* __restrict__ mu1, const float* __restrict__ va1,
    const float* __restrict__ g2, const float* __restrict__ be2,
    const float* __restrict__ mu2, const float* __restrict__ va2,
    short* __restrict__ w2b, short* __restrict__ w3ab, short* __restrict__ w3bb,
    short* __restrict__ w4b, float* __restrict__ sc1, float* __restrict__ sh1,
    float* __restrict__ sc2, float* __restrict__ sh2){
  int i = blockIdx.x*256 + threadIdx.x;
  if (i < 256*128) w2b[i] = f2bf(w2[i]);
  if (i < 512*512){
    int f = i >> 9, e = i & 511;
    short v = f2bf(w3[i]);
    if (e < 256) w3ab[f*256 + e] = v; else w3bb[f*256 + (e-256)] = v;
  }
  if (i < 384*512) w4b[i] = f2bf(w4[i]);
  if (i < 128){ float s = g1[i]*rsqrtf(va1[i] + BN_EPS_C); sc1[i]=s; sh1[i]=be1[i]-mu1[i]*s; }
  if (i < 512){ float s = g2[i]*rsqrtf(va2[i] + BN_EPS_C); sc2[i]=s; sh2[i]=be2[i]-mu2[i]*s; }
}

// ---------------- launcher ----------------
extern "C" void kernel_launch(void* const* d_in, const int* in_sizes, int n_in,
                              void* d_out, int out_size, void* d_ws, size_t ws_size,
                              hipStream_t stream){
  const float* points = (const float*)d_in[0];
  const float* w1  = (const float*)d_in[1];
  const float* g1  = (const float*)d_in[2];
  const float* be1 = (const float*)d_in[3];
  const float* mu1 = (const float*)d_in[4];
  const float* va1 = (const float*)d_in[5];
  const float* w2  = (const float*)d_in[6];
  const float* b2  = (const float*)d_in[7];
  const float* w3  = (const float*)d_in[8];
  const float* g2  = (const float*)d_in[9];
  const float* be2 = (const float*)d_in[10];
  const float* mu2 = (const float*)d_in[11];
  const float* va2 = (const float*)d_in[12];
  const float* w4  = (const float*)d_in[13];
  const float* b4  = (const float*)d_in[14];
  float* tokens  = (float*)d_out;                       // [PM, 384]
  float* centers = (float*)d_out + (size_t)PM*PTOK;     // [PM, 3]

  // ---- fixed workspace region (~25.1 MB) ----
  char* ws = (char*)d_ws;
  float* grp  = (float*)(ws + 0);              // 262144x3 fp32  = 3 MB
  short* gbuf = (short*)(ws + 3145728ull);     // 8192x256 bf16  = 4 MB
  float* Hbuf = (float*)(ws + 7340032ull);     // 8192x512 fp32  = 16 MB
  short* w2b  = (short*)(ws + 24117248ull);    // 256x128 bf16
  short* w3ab = (short*)(ws + 24182784ull);    // 512x256 bf16
  short* w3bb = (short*)(ws + 24444928ull);    // 512x256 bf16
  short* w4b  = (short*)(ws + 24707072ull);    // 384x512 bf16
  float* sc1  = (float*)(ws + 25100288ull);
  float* sh1  = (float*)(ws + 25100800ull);
  float* sc2  = (float*)(ws + 25101312ull);
  float* sh2  = (float*)(ws + 25103360ull);
  const size_t sliceBase = 25105408ull;

  // ---- adaptive row-slicing: peak slice use = 1792 bytes/row ----
  size_t avail = (ws_size > sliceBase) ? (ws_size - sliceBase) : 0;
  long long smax = (long long)(avail / 1792u);
  int S = (int)((smax / 4096) * 4096);
  if (S > PMK) S = PMK;
  if (S < 4096) S = 4096;   // below ~32 MB ws nothing fits; best effort
  char* sl = ws + sliceBase;

  prep_kernel<<<1024, 256, 0, stream>>>(w2, w3, w4, g1, be1, mu1, va1, g2, be2, mu2, va2,
                                        w2b, w3ab, w3bb, w4b, sc1, sh1, sc2, sh2);
  fps_kernel<<<PB, 1024, 0, stream>>>(points, centers);
  knn_kernel<<<PM, 256, 0, stream>>>(points, centers, grp);

  for (int r0 = 0; r0 < PMK; r0 += S){
    int rows = (PMK - r0 < S) ? (PMK - r0) : S;    // multiple of 4096
    int g0 = r0 >> 5, ng = rows >> 5;              // groups in slice
    short* f1 = (short*)(sl + 0);                  // rows x 128 bf16
    short* f2 = (short*)(sl + (size_t)S*256);      // rows x 256 bf16
    short* f3 = (short*)(sl + (size_t)S*768);      // rows x 512 bf16

    layer1_kernel<<<(rows*128)/256, 256, 0, stream>>>(grp + (size_t)r0*3, w1, sc1, sh1, f1);
    // f2 = f1 @ w2^T + b2, fused g = maxpool_k(f2)   [NB=2]
    gemm_bt<3><<<(rows/128)*2, 256, 0, stream>>>(f1, w2b, nullptr, f2, 256, 128,
                                                 b2, nullptr, nullptr,
                                                 gbuf + (size_t)g0*256, nullptr);
    // H = g @ w3[:, :256]^T   [NB=4]
    gemm_bt<0><<<(ng/128)*4, 256, 0, stream>>>(gbuf + (size_t)g0*256, w3ab,
                                               Hbuf + (size_t)g0*512, nullptr, 512, 256,
                                               nullptr, nullptr, nullptr, nullptr, nullptr);
    // f3 = relu(bn2(f2 @ w3[:, 256:]^T + H[group]))   [NB=4]
    gemm_bt<2><<<(rows/128)*4, 256, 0, stream>>>(f2, w3bb, nullptr, f3, 512, 256,
                                                 Hbuf + (size_t)g0*512, sc2, sh2,
                                                 nullptr, nullptr);
    // tokens = maxpool_k(f3 @ w4^T + b4), f4 never materialized   [NB=3]
    gemm_bt<4><<<(rows/128)*3, 256, 0, stream>>>(f3, w4b, nullptr, nullptr, 384, 512,
                                                 b4, nullptr, nullptr,
                                                 nullptr, tokens + (size_t)g0*384);
  }
}